// Round 1
// baseline (2836.330 us; speedup 1.0000x reference)
//
#include <hip/hip_runtime.h>
#include <hip/hip_bf16.h>
#include <cstdint>
#include <cstddef>

// B=64 T=512 E=768 H=256 L=9.  BiLSTM + linear + CRF loglik (scalar out).
// R7: break the 8-CU ceiling of the recurrence.
//  - lstm_k: 32 WGs = 2 dirs x 4 batch-groups x 4 hidden-slices (64 hu each).
//    Per-step h exchange via agent-scope (LLC-coherent) atomics + per-(d,bg)
//    publish counter; wave0-only poll; cooperative launch for co-residency.
//    MFMA B-frags load directly from the exchange buffer into registers
//    (no LDS h buffer at all; LDS keeps a 1KB scatter->coalesce tile).
//  - log2-domain gates: W/bias rows prescaled by log2(e) (2*log2e for g),
//    sigmoid/tanh via exp2 + shared-rcp fused forms (~30% less epilogue VALU).

typedef __attribute__((ext_vector_type(8))) short short8;
typedef __attribute__((ext_vector_type(4))) float floatx4;
typedef __attribute__((ext_vector_type(2))) float floatx2;
typedef __attribute__((ext_vector_type(8))) int v8i;
typedef unsigned short ushort_t;
typedef unsigned char uchar_t;
typedef unsigned int uint_t;
typedef unsigned long long ull_t;

#define NB   64
#define NT   512
#define NE   768
#define NH   256
#define NL   9
#define NG   1024   // 4*H
#define NCC  2048   // both dirs' gates

__device__ inline float b2f(ushort_t u) {
    union { uint_t i; float f; } v; v.i = ((uint_t)u) << 16; return v.f;
}
__device__ inline float asf(uint_t u) {
    union { uint_t i; float f; } v; v.i = u; return v.f;
}
__device__ inline ushort_t f2b(float f) {
    union { float f; uint_t i; } v; v.f = f;
    uint_t r = (v.i + 0x7FFFu + ((v.i >> 16) & 1u)) >> 16;
    return (ushort_t)r;
}

// ---------------- K1: embeddings (B,T,E) f32 -> xbf (T,B,E) bf16 ------------
__global__ void conv_x(const float* __restrict__ emb, ushort_t* __restrict__ xbf) {
    int id = blockIdx.x * blockDim.x + threadIdx.x;      // over T*B*(E/4)
    int t  = id / (NB * (NE / 4));
    int rm = id - t * (NB * (NE / 4));
    int b  = rm / (NE / 4);
    int e4 = rm - b * (NE / 4);
    const float4 v = *(const float4*)(emb + ((size_t)b * NT + t) * NE + e4 * 4);
    ushort_t o[4] = { f2b(v.x), f2b(v.y), f2b(v.z), f2b(v.w) };
    *(uint2*)(xbf + ((size_t)t * NB + b) * NE + e4 * 4) = *(const uint2*)o;
}

// ---------------- K1b: weights. Row interleave: row' = d*1024 + hu*4 + gate -
// Rows prescaled: i,f,o by log2(e); g by 2*log2(e)  (log2-domain gates).
__global__ void conv_w(const float* __restrict__ Wihf, const float* __restrict__ Wihb,
                       const float* __restrict__ Whhf, const float* __restrict__ Whhb,
                       const float* __restrict__ bf,   const float* __restrict__ bb,
                       ushort_t* __restrict__ wcat, uchar_t* __restrict__ whh8,
                       float* __restrict__ bias, uint_t* __restrict__ cnt) {
    int idx = blockIdx.x * blockDim.x + threadIdx.x;
    const int NW1 = NCC * NE;            // 1572864
    const int NW2 = NCC * NH / 2;        // 262144 fp8 pairs
    const float SC1 = 1.4426950408889634f;
    const float SC2 = 2.8853900817779268f;
    if (idx < NW1) {
        int rowp = idx / NE, col = idx - rowp * NE;
        int d = rowp >> 10, rr = rowp & 1023;
        int hu = rr >> 2, gate = rr & 3;
        float sc = (gate == 2) ? SC2 : SC1;
        const float* W = d ? Wihb : Wihf;
        wcat[idx] = f2b(W[(size_t)(gate * NH + hu) * NE + col] * sc);
    } else if (idx < NW1 + NW2) {
        int j = idx - NW1;
        int rowp = j >> 7, kp = (j & 127) * 2;
        int d = rowp >> 10, rr = rowp & 1023;
        int hu = rr >> 2, gate = rr & 3;
        float sc = (gate == 2) ? SC2 : SC1;
        const float* W = d ? Whhb : Whhf;
        float f0 = W[(size_t)(gate * NH + hu) * NH + kp] * sc;
        float f1 = W[(size_t)(gate * NH + hu) * NH + kp + 1] * sc;
        uint_t pk = __builtin_amdgcn_cvt_pk_fp8_f32(f0, f1, 0, false);
        *(ushort_t*)(whh8 + (size_t)rowp * NH + kp) = (ushort_t)(pk & 0xFFFF);
    } else if (idx < NW1 + NW2 + NCC) {
        int rowp = idx - NW1 - NW2;
        int d = rowp >> 10, rr = rowp & 1023;
        int hu = rr >> 2, gate = rr & 3;
        float sc = (gate == 2) ? SC2 : SC1;
        bias[rowp] = (d ? bb : bf)[gate * NH + hu] * sc;
    } else if (idx < NW1 + NW2 + NCC + 8) {
        cnt[idx - (NW1 + NW2 + NCC)] = 0;   // publish counters, zeroed per launch
    }
}

// ---------------- K2: xg = xbf(32768x768) @ wcat^T(2048x768) + bias ---------
__global__ __launch_bounds__(256) void gemm_xg(const ushort_t* __restrict__ A,
                                               const ushort_t* __restrict__ W,
                                               const float* __restrict__ bias,
                                               ushort_t* __restrict__ C) {
    __shared__ ushort_t As[128 * 72];
    __shared__ ushort_t Bs[128 * 72];
    const int tid = threadIdx.x;
    const int wave = tid >> 6, lane = tid & 63;
    const int q = lane >> 4, m16 = lane & 15;
    const int wm = wave & 1, wn = wave >> 1;
    const int m0 = blockIdx.y * 128, n0 = blockIdx.x * 128;

    floatx4 acc[4][4];
    #pragma unroll
    for (int i = 0; i < 4; ++i)
        #pragma unroll
        for (int j = 0; j < 4; ++j) acc[i][j] = (floatx4){0.f, 0.f, 0.f, 0.f};

    for (int kt = 0; kt < NE / 64; ++kt) {
        __syncthreads();
        #pragma unroll
        for (int it = 0; it < 4; ++it) {
            int chunk = tid + it * 256;         // 0..1023
            int row = chunk >> 3, kc = chunk & 7;
            *(uint4*)(&As[row * 72 + kc * 8]) =
                *(const uint4*)(A + (size_t)(m0 + row) * NE + kt * 64 + kc * 8);
            *(uint4*)(&Bs[row * 72 + kc * 8]) =
                *(const uint4*)(W + (size_t)(n0 + row) * NE + kt * 64 + kc * 8);
        }
        __syncthreads();
        #pragma unroll
        for (int ks = 0; ks < 2; ++ks) {
            short8 af[4], bfr[4];
            #pragma unroll
            for (int mt = 0; mt < 4; ++mt)
                af[mt] = *(const short8*)(&As[(wm * 64 + mt * 16 + m16) * 72 + ks * 32 + q * 8]);
            #pragma unroll
            for (int nt = 0; nt < 4; ++nt)
                bfr[nt] = *(const short8*)(&Bs[(wn * 64 + nt * 16 + m16) * 72 + ks * 32 + q * 8]);
            #pragma unroll
            for (int mt = 0; mt < 4; ++mt)
                #pragma unroll
                for (int nt = 0; nt < 4; ++nt)
                    acc[mt][nt] = __builtin_amdgcn_mfma_f32_16x16x32_bf16(
                        af[mt], bfr[nt], acc[mt][nt], 0, 0, 0);
        }
    }
    float bcol[4];
    #pragma unroll
    for (int nt = 0; nt < 4; ++nt) bcol[nt] = bias[n0 + wn * 64 + nt * 16 + m16];
    #pragma unroll
    for (int mt = 0; mt < 4; ++mt)
        #pragma unroll
        for (int nt = 0; nt < 4; ++nt) {
            int gn = n0 + wn * 64 + nt * 16 + m16;
            #pragma unroll
            for (int r = 0; r < 4; ++r) {
                int gm = m0 + wm * 64 + mt * 16 + q * 4 + r;
                C[(size_t)gm * NCC + gn] = f2b(acc[mt][nt][r] + bcol[nt]);
            }
        }
}

// ---------------- K3: recurrence, 32 WGs = 2 dirs x 4 bg x 4 hu-slices ------
// Each WG owns 256 gate rows (64 hu) of one (dir, batch-group).  Per step:
// MFMA (B-frags in regs from LLC) -> log2-domain gate epilogue -> LDS tile ->
// publish fp8 slice via agent-scope atomics -> counter release -> wave0 poll
// -> load next-step B-frags.  Zero LDS h buffer; 3 barriers/step.
__device__ inline uchar_t lstm_gate(floatx4 a, ull_t xr, float& cc) {
    uint_t lo = (uint_t)xr, hi = (uint_t)(xr >> 32);
    float pi = a[0] + asf(lo << 16);
    float pf = a[1] + asf(lo & 0xffff0000u);
    float pg = a[2] + asf(hi << 16);
    float po = a[3] + asf(hi & 0xffff0000u);
    // inputs are prescaled: pi,pf,po = log2e*x ; pg = 2*log2e*g
    float ei = __builtin_amdgcn_exp2f(-fmaxf(pi, -80.f));   // 2^-pi = e^-x
    float ef = __builtin_amdgcn_exp2f(-fmaxf(pf, -80.f));
    float eo = __builtin_amdgcn_exp2f(-fmaxf(po, -80.f));
    float ug = __builtin_amdgcn_exp2f(fminf(pg, 80.f));     // e^{2g}
    float A  = 1.f + ei, Bv = 1.f + ug, C = 1.f + ef;
    // c' = c/C + (Bv-2)/(A*Bv)   [sig(f)*c + sig(i)*tanh(g)], one rcp
    float AB  = A * Bv;
    float num = fmaf(Bv - 2.f, C, cc * AB);
    float cn  = num * __builtin_amdgcn_rcpf(C * AB);
    cc = cn;
    // h = tanh(c')*sig(o) = (uc-1)/((uc+1)*(1+eo)), one rcp
    float uc = __builtin_amdgcn_exp2f(fminf(cn * 2.8853900817779268f, 80.f));
    float h  = (uc - 1.f) * __builtin_amdgcn_rcpf((uc + 1.f) * (1.f + eo));
    uint_t pk = __builtin_amdgcn_cvt_pk_fp8_f32(h, h, 0, false);
    return (uchar_t)(pk & 0xFF);
}

__global__ __launch_bounds__(512, 2) void lstm_k(const ushort_t* __restrict__ xg,
                                                 const uchar_t* __restrict__ whh8,
                                                 uchar_t* __restrict__ hhist8,
                                                 uchar_t* __restrict__ xchg,
                                                 uint_t* __restrict__ cnt) {
    const int bid = blockIdx.x;
    const int d   = bid >> 4;          // direction
    const int bg  = (bid >> 2) & 3;    // batch group
    const int sl  = bid & 3;           // hidden slice
    const int cidx = d * 4 + bg;
    const int tid = threadIdx.x;
    const int w = tid >> 6, lane = tid & 63;
    const int q = lane >> 4, m16 = lane & 15;
    const int bl = bg * 16 + m16;      // this lane's batch (global)

    __shared__ uchar_t hown[16 * 72];  // own fp8 slice, [batch][hu_local]

    // Weight A-frags: rows' = d*1024 + sl*256 + w*32 + mt*16 + m16, 32B/kh.
    const uchar_t* wp = whh8 + (size_t)(d * NG + sl * 256 + w * 32) * NH;
    v8i wreg[2][2];
    #pragma unroll
    for (int mt = 0; mt < 2; ++mt)
        #pragma unroll
        for (int kh = 0; kh < 2; ++kh)
            wreg[mt][kh] = *(const v8i*)(wp + (size_t)(mt * 16 + m16) * NH + kh * 128 + q * 32);

    float c0 = 0.f, c1 = 0.f;
    v8i hf0 = {0,0,0,0,0,0,0,0};
    v8i hf1 = {0,0,0,0,0,0,0,0};

    const ushort_t* xbase = xg + (size_t)d * NG + sl * 256 + w * 32 + q * 4;
    int t = d ? (NT - 1) : 0;
    ull_t xr0 = *(const ull_t*)(xbase + (size_t)(t * NB + bl) * NCC);
    ull_t xr1 = *(const ull_t*)(xbase + (size_t)(t * NB + bl) * NCC + 16);
    uint_t* cntp = cnt + cidx;
    const int scl = 0x7f7f7f7f;                 // e8m0 scale = 1.0

    #pragma unroll 1
    for (int s = 0; s < NT; ++s) {
        floatx4 a0 = (floatx4){0.f, 0.f, 0.f, 0.f};
        floatx4 a1 = (floatx4){0.f, 0.f, 0.f, 0.f};
        a0 = __builtin_amdgcn_mfma_scale_f32_16x16x128_f8f6f4(wreg[0][0], hf0, a0, 0, 0, 0, scl, 0, scl);
        a1 = __builtin_amdgcn_mfma_scale_f32_16x16x128_f8f6f4(wreg[1][0], hf0, a1, 0, 0, 0, scl, 0, scl);
        a0 = __builtin_amdgcn_mfma_scale_f32_16x16x128_f8f6f4(wreg[0][1], hf1, a0, 0, 0, 0, scl, 0, scl);
        a1 = __builtin_amdgcn_mfma_scale_f32_16x16x128_f8f6f4(wreg[1][1], hf1, a1, 0, 0, 0, scl, 0, scl);

        // Epilogue: hu_local = w*8 + mt*4 + q, gates = C regs 0..3.
        hown[m16 * 72 + w * 8 + q]     = lstm_gate(a0, xr0, c0);
        hown[m16 * 72 + w * 8 + 4 + q] = lstm_gate(a1, xr1, c1);
        __syncthreads();                               // #1: tile complete

        // Publish: 128 threads, 8B each -> xchg (agent atomics) + hhist.
        if (tid < 128) {
            const int b = tid >> 3, j = tid & 7;
            ull_t v = *(const ull_t*)(&hown[b * 72 + j * 8]);
            __hip_atomic_store(
                (ull_t*)(xchg + ((size_t)(cidx * 2 + ((s + 1) & 1)) * 16 + b) * NH + sl * 64 + j * 8),
                v, __ATOMIC_RELAXED, __HIP_MEMORY_SCOPE_AGENT);
            *(ull_t*)(hhist8 + ((size_t)(d * NT + t) * NB + bg * 16 + b) * NH + sl * 64 + j * 8) = v;
        }
        asm volatile("s_waitcnt vmcnt(0)" ::: "memory");  // own stores at LLC
        __syncthreads();                               // #2: all WG stores done
        if (tid == 0)
            __hip_atomic_fetch_add(cntp, 1u, __ATOMIC_RELEASE, __HIP_MEMORY_SCOPE_AGENT);
        if (s == NT - 1) break;

        // Prefetch next step's xg while waiting on partners.
        t = d ? (NT - 2 - s) : (s + 1);
        xr0 = *(const ull_t*)(xbase + (size_t)(t * NB + bl) * NCC);
        xr1 = *(const ull_t*)(xbase + (size_t)(t * NB + bl) * NCC + 16);

        if (w == 0) {                                  // one coalesced poll/WG
            const uint_t tgt = 4u * (uint_t)(s + 1);
            while (__hip_atomic_load(cntp, __ATOMIC_RELAXED, __HIP_MEMORY_SCOPE_AGENT) < tgt)
                __builtin_amdgcn_s_sleep(1);
        }
        __syncthreads();                               // #3: h ready at LLC

        // B-frags for next step: lane = batch m16, k-chunk q*32 (+128).
        const uchar_t* hq = xchg + ((size_t)(cidx * 2 + ((s + 1) & 1)) * 16 + m16) * NH + q * 32;
        union V8 { v8i v; ull_t u[4]; } u0, u1;
        #pragma unroll
        for (int j = 0; j < 4; ++j) {
            u0.u[j] = __hip_atomic_load((const ull_t*)(hq + j * 8),
                                        __ATOMIC_RELAXED, __HIP_MEMORY_SCOPE_AGENT);
            u1.u[j] = __hip_atomic_load((const ull_t*)(hq + 128 + j * 8),
                                        __ATOMIC_RELAXED, __HIP_MEMORY_SCOPE_AGENT);
        }
        hf0 = u0.v; hf1 = u1.v;
    }
}

// ---------------- K4: em[t,b,l] = feats . W_lin[l] + b_lin ------------------
__global__ void em_k(const uchar_t* __restrict__ hhist8, const float* __restrict__ Wlin,
                     const float* __restrict__ blin, float* __restrict__ em) {
    const int t = blockIdx.x;
    const int tid = threadIdx.x;          // 576 threads
    __shared__ float Ws[NL * 520];
    for (int idx = tid; idx < NL * 2 * NH; idx += 576) {
        int l = idx >> 9, k = idx & 511;
        Ws[l * 520 + k] = Wlin[l * 2 * NH + k];
    }
    __syncthreads();
    const int b = tid / NL, l = tid - b * NL;
    const uchar_t* hf = hhist8 + ((size_t)t * NB + b) * NH;
    const uchar_t* hb = hhist8 + ((size_t)(NT + t) * NB + b) * NH;
    float acc = blin[l];
    #pragma unroll 4
    for (int kc = 0; kc < NH / 4; ++kc) {
        uint_t u = *(const uint_t*)(hf + kc * 4);
        floatx2 p0 = __builtin_amdgcn_cvt_pk_f32_fp8(u, false);
        floatx2 p1 = __builtin_amdgcn_cvt_pk_f32_fp8(u, true);
        acc += p0.x * Ws[l * 520 + kc * 4]     + p0.y * Ws[l * 520 + kc * 4 + 1]
             + p1.x * Ws[l * 520 + kc * 4 + 2] + p1.y * Ws[l * 520 + kc * 4 + 3];
    }
    #pragma unroll 4
    for (int kc = 0; kc < NH / 4; ++kc) {
        uint_t u = *(const uint_t*)(hb + kc * 4);
        floatx2 p0 = __builtin_amdgcn_cvt_pk_f32_fp8(u, false);
        floatx2 p1 = __builtin_amdgcn_cvt_pk_f32_fp8(u, true);
        acc += p0.x * Ws[l * 520 + NH + kc * 4]     + p0.y * Ws[l * 520 + NH + kc * 4 + 1]
             + p1.x * Ws[l * 520 + NH + kc * 4 + 2] + p1.y * Ws[l * 520 + NH + kc * 4 + 3];
    }
    em[((size_t)t * NB + b) * NL + l] = acc;
}

// ---------------- K5: CRF numerator per batch (parallel over t) -------------
__global__ void num_k(const float* __restrict__ em, const int* __restrict__ mask,
                      const int* __restrict__ labels, const float* __restrict__ start,
                      const float* __restrict__ endt, const float* __restrict__ trans,
                      float* __restrict__ numbuf) {
    const int b = blockIdx.x;       // 64 blocks x 64 threads (1 wave)
    const int lane = threadIdx.x;
    int cntm = 0;
    for (int t = lane; t < NT; t += 64) cntm += (mask[b * NT + t] != 0);
    #pragma unroll
    for (int off = 32; off > 0; off >>= 1) cntm += __shfl_down(cntm, off);
    const int len = __shfl(cntm, 0);

    float part = 0.f;
    for (int t = lane; t < NT; t += 64) {
        if (t >= 1 && t < len) {
            int tp = labels[b * NT + t - 1];
            int tg = labels[b * NT + t];
            part += trans[tp * NL + tg] + em[((size_t)t * NB + b) * NL + tg];
        }
    }
    #pragma unroll
    for (int off = 32; off > 0; off >>= 1) part += __shfl_down(part, off);
    if (lane == 0) {
        int tag0 = labels[b * NT];
        numbuf[b] = part + start[tag0] + em[(size_t)b * NL + tag0]
                  + endt[labels[b * NT + len - 1]];
    }
}

// ---------------- K6: CRF forward (logZ), diff = logZ - num -----------------
__global__ void crf_k(const float* __restrict__ em, const int* __restrict__ mask,
                      const float* __restrict__ start, const float* __restrict__ endt,
                      const float* __restrict__ trans, const float* __restrict__ numbuf,
                      float* __restrict__ diff) {
    const int b = blockIdx.x;
    const int lane = threadIdx.x;       // 64 threads = 1 wave
    int cnt = 0;
    for (int t = lane; t < NT; t += 64) cnt += (mask[b * NT + t] != 0);
    #pragma unroll
    for (int off = 32; off > 0; off >>= 1) cnt += __shfl_down(cnt, off);
    const int len = __shfl(cnt, 0);

    float tcol[NL];
    #pragma unroll
    for (int i = 0; i < NL; ++i) tcol[i] = (lane < NL) ? trans[i * NL + lane] : 0.f;
    float endv = (lane < NL) ? endt[lane] : 0.f;
    float score = (lane < NL) ? start[lane] + em[(size_t)b * NL + lane] : -1e30f;

    for (int t = 1; t < len; ++t) {
        float emv = (lane < NL) ? em[((size_t)t * NB + b) * NL + lane] : 0.f;
        float sv[NL];
        #pragma unroll
        for (int i = 0; i < NL; ++i) sv[i] = __shfl(score, i) + tcol[i];
        float m = sv[0];
        #pragma unroll
        for (int i = 1; i < NL; ++i) m = fmaxf(m, sv[i]);
        float sum = 0.f;
        #pragma unroll
        for (int i = 0; i < NL; ++i) sum += __expf(sv[i] - m);
        float nxt = m + __logf(sum) + emv;
        if (lane < NL) score = nxt;
    }
    float v = (lane < NL) ? score + endv : -1e30f;
    float m = -1e30f;
    float sv[NL];
    #pragma unroll
    for (int i = 0; i < NL; ++i) { sv[i] = __shfl(v, i); m = fmaxf(m, sv[i]); }
    float sum = 0.f;
    #pragma unroll
    for (int i = 0; i < NL; ++i) sum += __expf(sv[i] - m);
    float logZ = m + __logf(sum);
    if (lane == 0) diff[b] = logZ - numbuf[b];
}

// ---------------- K7: mean over batch -> d_out ------------------------------
__global__ void final_k(const float* __restrict__ diff, float* __restrict__ out) {
    float v = diff[threadIdx.x];
    #pragma unroll
    for (int off = 32; off > 0; off >>= 1) v += __shfl_down(v, off);
    if (threadIdx.x == 0) out[0] = v * (1.0f / NB);
}

extern "C" void kernel_launch(void* const* d_in, const int* in_sizes, int n_in,
                              void* d_out, int out_size, void* d_ws, size_t ws_size,
                              hipStream_t stream) {
    const float* emb   = (const float*)d_in[0];
    const float* Wihf  = (const float*)d_in[1];
    const float* Whhf  = (const float*)d_in[2];
    const float* bf    = (const float*)d_in[3];
    const float* Wihb  = (const float*)d_in[4];
    const float* Whhb  = (const float*)d_in[5];
    const float* bb    = (const float*)d_in[6];
    const float* Wlin  = (const float*)d_in[7];
    const float* blin  = (const float*)d_in[8];
    const float* start = (const float*)d_in[9];
    const float* endt  = (const float*)d_in[10];
    const float* trans = (const float*)d_in[11];
    const int*   mask  = (const int*)d_in[12];
    const int*   labels= (const int*)d_in[13];

    char* ws = (char*)d_ws;
    ushort_t* xbf   = (ushort_t*)(ws + 0);                     // 50,331,648
    ushort_t* wcat  = (ushort_t*)(ws + 50331648);              //  3,145,728
    uchar_t*  whh8  = (uchar_t*) (ws + 53477376);              //    524,288
    float*    bias  = (float*)   (ws + 54001664);              //      8,192
    ushort_t* xg    = (ushort_t*)(ws + 54009856);              // 134,217,728
    uchar_t*  hh8   = (uchar_t*) (ws + 188227584);             // 16,777,216
    float*    em    = (float*)   (ws + 205004800);             //  1,179,648
    float*    numb  = (float*)   (ws + 206184448);             //        256
    float*    diff  = (float*)   (ws + 206184704);             //        256
    uchar_t*  xchg  = (uchar_t*) (ws + 206184960);             //     65,536
    uint_t*   cnt   = (uint_t*)  (ws + 206250496);             //         32

    conv_x<<<NT * NB * (NE / 4) / 256, 256, 0, stream>>>(emb, xbf);
    {
        int convw_n = NCC * NE + NCC * NH / 2 + NCC + 8;
        conv_w<<<(convw_n + 255) / 256, 256, 0, stream>>>(
            Wihf, Wihb, Whhf, Whhb, bf, bb, wcat, whh8, bias, cnt);
    }
    gemm_xg<<<dim3(NCC / 128, NT * NB / 128), 256, 0, stream>>>(xbf, wcat, bias, xg);
    {
        void* args[] = { (void*)&xg, (void*)&whh8, (void*)&hh8, (void*)&xchg, (void*)&cnt };
        hipError_t ce = hipLaunchCooperativeKernel((const void*)lstm_k, dim3(32), dim3(512),
                                                   args, 0, stream);
        if (ce != hipSuccess) {
            // 32 small WGs on an otherwise-empty 256-CU device: all resident.
            lstm_k<<<32, 512, 0, stream>>>(xg, whh8, hh8, xchg, cnt);
        }
    }
    em_k<<<NT, 576, 0, stream>>>(hh8, Wlin, blin, em);
    num_k<<<NB, 64, 0, stream>>>(em, mask, labels, start, endt, trans, numb);
    crf_k<<<NB, 64, 0, stream>>>(em, mask, start, endt, trans, numb, diff);
    final_k<<<1, 64, 0, stream>>>(diff, (float*)d_out);
}

// Round 2
// 1821.055 us; speedup vs baseline: 1.5575x; 1.5575x over previous
//
#include <hip/hip_runtime.h>
#include <hip/hip_bf16.h>
#include <cstdint>
#include <cstddef>

// B=64 T=512 E=768 H=256 L=9.  BiLSTM + linear + CRF loglik (scalar out).
// R8: R6's zero-sync 8-WG recurrence structure (2 dirs x 4 batch-groups,
// fp8 W_hh pinned in AGPRs, h in LDS fp8 double buffer, one barrier/step,
// coalesced fp8 h-history write)  +  R7's harness-verified log2-domain gate
// epilogue (weights prescaled by log2e; 5 exp2 + 2 rcp per h instead of
// 10 trans; bf16 unpack via bit-ops).  R7's cross-WG split is reverted:
// measured, the per-step LLC sync chain (~4 round-trips) costs more than
// the entire per-step compute.  Epilogue VALU/trans issue is the measured
// bottleneck (VALUBusy ~77% of active CUs in R6) -> cut it ~2x.

typedef __attribute__((ext_vector_type(8))) short short8;
typedef __attribute__((ext_vector_type(4))) float floatx4;
typedef __attribute__((ext_vector_type(2))) float floatx2;
typedef __attribute__((ext_vector_type(8))) int v8i;
typedef unsigned short ushort_t;
typedef unsigned char uchar_t;
typedef unsigned int uint_t;
typedef unsigned long long ull_t;

#define NB   64
#define NT   512
#define NE   768
#define NH   256
#define NL   9
#define NG   1024   // 4*H
#define NCC  2048   // both dirs' gates
#define HPAD 272    // LDS h row stride (bytes, fp8): 17x16B -> 16B-aligned rows

__device__ inline float asf(uint_t u) {
    union { uint_t i; float f; } v; v.i = u; return v.f;
}
__device__ inline ushort_t f2b(float f) {
    union { float f; uint_t i; } v; v.f = f;
    uint_t r = (v.i + 0x7FFFu + ((v.i >> 16) & 1u)) >> 16;
    return (ushort_t)r;
}

// ---------------- K1: embeddings (B,T,E) f32 -> xbf (T,B,E) bf16 ------------
__global__ void conv_x(const float* __restrict__ emb, ushort_t* __restrict__ xbf) {
    int id = blockIdx.x * blockDim.x + threadIdx.x;      // over T*B*(E/4)
    int t  = id / (NB * (NE / 4));
    int rm = id - t * (NB * (NE / 4));
    int b  = rm / (NE / 4);
    int e4 = rm - b * (NE / 4);
    const float4 v = *(const float4*)(emb + ((size_t)b * NT + t) * NE + e4 * 4);
    ushort_t o[4] = { f2b(v.x), f2b(v.y), f2b(v.z), f2b(v.w) };
    *(uint2*)(xbf + ((size_t)t * NB + b) * NE + e4 * 4) = *(const uint2*)o;
}

// ---------------- K1b: weights. Row interleave: row' = d*1024 + hu*4 + gate -
// Rows prescaled: i,f,o by log2(e); g by 2*log2(e)  (log2-domain gates).
__global__ void conv_w(const float* __restrict__ Wihf, const float* __restrict__ Wihb,
                       const float* __restrict__ Whhf, const float* __restrict__ Whhb,
                       const float* __restrict__ bf,   const float* __restrict__ bb,
                       ushort_t* __restrict__ wcat, uchar_t* __restrict__ whh8,
                       float* __restrict__ bias) {
    int idx = blockIdx.x * blockDim.x + threadIdx.x;
    const int NW1 = NCC * NE;            // 1572864
    const int NW2 = NCC * NH / 2;        // 262144 fp8 pairs
    const float SC1 = 1.4426950408889634f;
    const float SC2 = 2.8853900817779268f;
    if (idx < NW1) {
        int rowp = idx / NE, col = idx - rowp * NE;
        int d = rowp >> 10, rr = rowp & 1023;
        int hu = rr >> 2, gate = rr & 3;
        float sc = (gate == 2) ? SC2 : SC1;
        const float* W = d ? Wihb : Wihf;
        wcat[idx] = f2b(W[(size_t)(gate * NH + hu) * NE + col] * sc);
    } else if (idx < NW1 + NW2) {
        int j = idx - NW1;
        int rowp = j >> 7, kp = (j & 127) * 2;
        int d = rowp >> 10, rr = rowp & 1023;
        int hu = rr >> 2, gate = rr & 3;
        float sc = (gate == 2) ? SC2 : SC1;
        const float* W = d ? Whhb : Whhf;
        float f0 = W[(size_t)(gate * NH + hu) * NH + kp] * sc;
        float f1 = W[(size_t)(gate * NH + hu) * NH + kp + 1] * sc;
        uint_t pk = __builtin_amdgcn_cvt_pk_fp8_f32(f0, f1, 0, false);
        *(ushort_t*)(whh8 + (size_t)rowp * NH + kp) = (ushort_t)(pk & 0xFFFF);
    } else if (idx < NW1 + NW2 + NCC) {
        int rowp = idx - NW1 - NW2;
        int d = rowp >> 10, rr = rowp & 1023;
        int hu = rr >> 2, gate = rr & 3;
        float sc = (gate == 2) ? SC2 : SC1;
        bias[rowp] = (d ? bb : bf)[gate * NH + hu] * sc;
    }
}

// ---------------- K2: xg = xbf(32768x768) @ wcat^T(2048x768) + bias ---------
__global__ __launch_bounds__(256) void gemm_xg(const ushort_t* __restrict__ A,
                                               const ushort_t* __restrict__ W,
                                               const float* __restrict__ bias,
                                               ushort_t* __restrict__ C) {
    __shared__ ushort_t As[128 * 72];
    __shared__ ushort_t Bs[128 * 72];
    const int tid = threadIdx.x;
    const int wave = tid >> 6, lane = tid & 63;
    const int q = lane >> 4, m16 = lane & 15;
    const int wm = wave & 1, wn = wave >> 1;
    const int m0 = blockIdx.y * 128, n0 = blockIdx.x * 128;

    floatx4 acc[4][4];
    #pragma unroll
    for (int i = 0; i < 4; ++i)
        #pragma unroll
        for (int j = 0; j < 4; ++j) acc[i][j] = (floatx4){0.f, 0.f, 0.f, 0.f};

    for (int kt = 0; kt < NE / 64; ++kt) {
        __syncthreads();
        #pragma unroll
        for (int it = 0; it < 4; ++it) {
            int chunk = tid + it * 256;         // 0..1023
            int row = chunk >> 3, kc = chunk & 7;
            *(uint4*)(&As[row * 72 + kc * 8]) =
                *(const uint4*)(A + (size_t)(m0 + row) * NE + kt * 64 + kc * 8);
            *(uint4*)(&Bs[row * 72 + kc * 8]) =
                *(const uint4*)(W + (size_t)(n0 + row) * NE + kt * 64 + kc * 8);
        }
        __syncthreads();
        #pragma unroll
        for (int ks = 0; ks < 2; ++ks) {
            short8 af[4], bfr[4];
            #pragma unroll
            for (int mt = 0; mt < 4; ++mt)
                af[mt] = *(const short8*)(&As[(wm * 64 + mt * 16 + m16) * 72 + ks * 32 + q * 8]);
            #pragma unroll
            for (int nt = 0; nt < 4; ++nt)
                bfr[nt] = *(const short8*)(&Bs[(wn * 64 + nt * 16 + m16) * 72 + ks * 32 + q * 8]);
            #pragma unroll
            for (int mt = 0; mt < 4; ++mt)
                #pragma unroll
                for (int nt = 0; nt < 4; ++nt)
                    acc[mt][nt] = __builtin_amdgcn_mfma_f32_16x16x32_bf16(
                        af[mt], bfr[nt], acc[mt][nt], 0, 0, 0);
        }
    }
    float bcol[4];
    #pragma unroll
    for (int nt = 0; nt < 4; ++nt) bcol[nt] = bias[n0 + wn * 64 + nt * 16 + m16];
    #pragma unroll
    for (int mt = 0; mt < 4; ++mt)
        #pragma unroll
        for (int nt = 0; nt < 4; ++nt) {
            int gn = n0 + wn * 64 + nt * 16 + m16;
            #pragma unroll
            for (int r = 0; r < 4; ++r) {
                int gm = m0 + wm * 64 + mt * 16 + q * 4 + r;
                C[(size_t)gm * NCC + gn] = f2b(acc[mt][nt][r] + bcol[nt]);
            }
        }
}

// ---------------- log2-domain LSTM gate (verified in R7) --------------------
// Inputs prescaled: pi,pf,po = log2e * preact ; pg = 2*log2e * preact.
// sig(x) = 1/(1+2^-px); tanh(g) = (2^pg - 1)/(2^pg + 1).
// c' = [cc*A*Bv + (Bv-2)*C] / (C*A*Bv)   -- one rcp
// h  = (uc-1) / ((uc+1)*(1+eo))          -- one rcp
// Clamps +-40: all intermediates finite even at |c| <= 512.
__device__ inline uchar_t lstm_gate(floatx4 a, ull_t xr, float& cc) {
    uint_t lo = (uint_t)xr, hi = (uint_t)(xr >> 32);
    float pi = a[0] + asf(lo << 16);
    float pf = a[1] + asf(lo & 0xffff0000u);
    float pg = a[2] + asf(hi << 16);
    float po = a[3] + asf(hi & 0xffff0000u);
    float ei = __builtin_amdgcn_exp2f(-fmaxf(pi, -40.f));   // e^-i
    float ef = __builtin_amdgcn_exp2f(-fmaxf(pf, -40.f));   // e^-f
    float eo = __builtin_amdgcn_exp2f(-fmaxf(po, -40.f));   // e^-o
    float ug = __builtin_amdgcn_exp2f(fminf(pg, 40.f));     // e^{2g}
    float A  = 1.f + ei, Bv = 1.f + ug, C = 1.f + ef;
    float AB  = A * Bv;
    float num = fmaf(Bv - 2.f, C, cc * AB);
    float cn  = num * __builtin_amdgcn_rcpf(C * AB);
    cc = cn;
    float uc = __builtin_amdgcn_exp2f(fminf(cn * 2.8853900817779268f, 40.f));
    float h  = (uc - 1.f) * __builtin_amdgcn_rcpf((uc + 1.f) * (1.f + eo));
    uint_t pk = __builtin_amdgcn_cvt_pk_fp8_f32(h, h, 0, false);
    return (uchar_t)(pk & 0xFF);
}

// ---------------- K3: recurrence, 8 WGs = 2 dirs x 4 batch-groups -----------
// 512 threads = 8 waves; wave w owns gate rows' [w*128, w*128+128) = hu
// [w*32,w*32+32) x 4 gates (interleaved).  fp8 weights in AGPRs (asm "+a"),
// MX-scaled MFMA K=128 with unit scales.  h: LDS fp8 double buffer, one
// barrier/step; h history written via coalesced 8B LDS->global copy.
__global__ __launch_bounds__(512, 2) void lstm_k(const ushort_t* __restrict__ xg,
                                                 const uchar_t* __restrict__ whh8,
                                                 uchar_t* __restrict__ hhist8) {
    const int d  = blockIdx.x >> 2;
    const int bg = blockIdx.x & 3;
    const int tid = threadIdx.x;
    const int w = tid >> 6, lane = tid & 63;
    const int q = lane >> 4, m16 = lane & 15;
    const int bl = bg * 16 + m16;               // this lane's batch (global)

    __shared__ uchar_t hb8[2][16 * HPAD];       // fp8 h, [local batch][hu]
    for (int i = tid; i < 16 * HPAD; i += 512) hb8[0][i] = 0;

    // Weight A-frags: rows' w*128+mt*16+m16, k = kh*128 + q*32 (32B each).
    const uchar_t* wp = whh8 + (size_t)(d * NG + w * 128) * NH;
    v8i wreg[8][2];
    #pragma unroll
    for (int mt = 0; mt < 8; ++mt)
        #pragma unroll
        for (int kh = 0; kh < 2; ++kh)
            wreg[mt][kh] = *(const v8i*)(wp + (size_t)(mt * 16 + m16) * NH + kh * 128 + q * 32);
    #pragma unroll
    for (int mt = 0; mt < 8; ++mt)
        #pragma unroll
        for (int kh = 0; kh < 2; ++kh)
            asm volatile("" : "+a"(wreg[mt][kh]));   // pin in AGPR class

    float c[8];
    #pragma unroll
    for (int i = 0; i < 8; ++i) c[i] = 0.f;
    __syncthreads();

    const int scl = 0x7f7f7f7f;                 // e8m0 scale = 1.0 in all bytes

    #pragma unroll 1
    for (int s = 0; s < NT; ++s) {
        const int t = d ? (NT - 1 - s) : s;

        // xg: 8B per m-tile (4 gates of one hu).  Prescaled by log2e.
        const ushort_t* xp = xg + (size_t)(t * NB + bl) * NCC + d * NG + w * 128;
        ull_t xr[8];
        #pragma unroll
        for (int mt = 0; mt < 8; ++mt)
            xr[mt] = *(const ull_t*)(xp + mt * 16 + q * 4);

        // B-frags: h_prev fp8 from LDS, 32B per k-half (lane n = batch m16).
        const uchar_t* hrow = &hb8[s & 1][m16 * HPAD];
        v8i hf0 = *(const v8i*)(hrow + q * 32);
        v8i hf1 = *(const v8i*)(hrow + 128 + q * 32);

        floatx4 acc[8];
        #pragma unroll
        for (int mt = 0; mt < 8; ++mt) acc[mt] = (floatx4){0.f, 0.f, 0.f, 0.f};
        #pragma unroll
        for (int mt = 0; mt < 8; ++mt)
            acc[mt] = __builtin_amdgcn_mfma_scale_f32_16x16x128_f8f6f4(
                wreg[mt][0], hf0, acc[mt], 0, 0, 0, scl, 0, scl);
        #pragma unroll
        for (int mt = 0; mt < 8; ++mt)
            acc[mt] = __builtin_amdgcn_mfma_scale_f32_16x16x128_f8f6f4(
                wreg[mt][1], hf1, acc[mt], 0, 0, 0, scl, 0, scl);

        // Epilogue: all 4 gates in-lane (C reg r = gate r of hu w*32+mt*4+q).
        uchar_t* hwr = &hb8[(s + 1) & 1][m16 * HPAD];
        #pragma unroll
        for (int mt = 0; mt < 8; ++mt)
            hwr[w * 32 + mt * 4 + q] = lstm_gate(acc[mt], xr[mt], c[mt]);
        __syncthreads();
        // Coalesced fp8 h-history write: 4KB per step per WG, 8B/thread.
        {
            int b = tid >> 5, off = (tid & 31) * 8;
            ull_t v = *(const ull_t*)(&hb8[(s + 1) & 1][b * HPAD + off]);
            *(ull_t*)(hhist8 + ((size_t)(d * NT + t) * NB + bg * 16 + b) * NH + off) = v;
        }
    }
}

// ---------------- K4: em[t,b,l] = feats . W_lin[l] + b_lin ------------------
__global__ void em_k(const uchar_t* __restrict__ hhist8, const float* __restrict__ Wlin,
                     const float* __restrict__ blin, float* __restrict__ em) {
    const int t = blockIdx.x;
    const int tid = threadIdx.x;          // 576 threads
    __shared__ float Ws[NL * 520];
    for (int idx = tid; idx < NL * 2 * NH; idx += 576) {
        int l = idx >> 9, k = idx & 511;
        Ws[l * 520 + k] = Wlin[l * 2 * NH + k];
    }
    __syncthreads();
    const int b = tid / NL, l = tid - b * NL;
    const uchar_t* hf = hhist8 + ((size_t)t * NB + b) * NH;
    const uchar_t* hb = hhist8 + ((size_t)(NT + t) * NB + b) * NH;
    float acc = blin[l];
    #pragma unroll 4
    for (int kc = 0; kc < NH / 4; ++kc) {
        uint_t u = *(const uint_t*)(hf + kc * 4);
        floatx2 p0 = __builtin_amdgcn_cvt_pk_f32_fp8(u, false);
        floatx2 p1 = __builtin_amdgcn_cvt_pk_f32_fp8(u, true);
        acc += p0.x * Ws[l * 520 + kc * 4]     + p0.y * Ws[l * 520 + kc * 4 + 1]
             + p1.x * Ws[l * 520 + kc * 4 + 2] + p1.y * Ws[l * 520 + kc * 4 + 3];
    }
    #pragma unroll 4
    for (int kc = 0; kc < NH / 4; ++kc) {
        uint_t u = *(const uint_t*)(hb + kc * 4);
        floatx2 p0 = __builtin_amdgcn_cvt_pk_f32_fp8(u, false);
        floatx2 p1 = __builtin_amdgcn_cvt_pk_f32_fp8(u, true);
        acc += p0.x * Ws[l * 520 + NH + kc * 4]     + p0.y * Ws[l * 520 + NH + kc * 4 + 1]
             + p1.x * Ws[l * 520 + NH + kc * 4 + 2] + p1.y * Ws[l * 520 + NH + kc * 4 + 3];
    }
    em[((size_t)t * NB + b) * NL + l] = acc;
}

// ---------------- K5: CRF numerator per batch (parallel over t) -------------
__global__ void num_k(const float* __restrict__ em, const int* __restrict__ mask,
                      const int* __restrict__ labels, const float* __restrict__ start,
                      const float* __restrict__ endt, const float* __restrict__ trans,
                      float* __restrict__ numbuf) {
    const int b = blockIdx.x;       // 64 blocks x 64 threads (1 wave)
    const int lane = threadIdx.x;
    int cntm = 0;
    for (int t = lane; t < NT; t += 64) cntm += (mask[b * NT + t] != 0);
    #pragma unroll
    for (int off = 32; off > 0; off >>= 1) cntm += __shfl_down(cntm, off);
    const int len = __shfl(cntm, 0);

    float part = 0.f;
    for (int t = lane; t < NT; t += 64) {
        if (t >= 1 && t < len) {
            int tp = labels[b * NT + t - 1];
            int tg = labels[b * NT + t];
            part += trans[tp * NL + tg] + em[((size_t)t * NB + b) * NL + tg];
        }
    }
    #pragma unroll
    for (int off = 32; off > 0; off >>= 1) part += __shfl_down(part, off);
    if (lane == 0) {
        int tag0 = labels[b * NT];
        numbuf[b] = part + start[tag0] + em[(size_t)b * NL + tag0]
                  + endt[labels[b * NT + len - 1]];
    }
}

// ---------------- K6: CRF forward (logZ), diff = logZ - num -----------------
__global__ void crf_k(const float* __restrict__ em, const int* __restrict__ mask,
                      const float* __restrict__ start, const float* __restrict__ endt,
                      const float* __restrict__ trans, const float* __restrict__ numbuf,
                      float* __restrict__ diff) {
    const int b = blockIdx.x;
    const int lane = threadIdx.x;       // 64 threads = 1 wave
    int cnt = 0;
    for (int t = lane; t < NT; t += 64) cnt += (mask[b * NT + t] != 0);
    #pragma unroll
    for (int off = 32; off > 0; off >>= 1) cnt += __shfl_down(cnt, off);
    const int len = __shfl(cnt, 0);

    float tcol[NL];
    #pragma unroll
    for (int i = 0; i < NL; ++i) tcol[i] = (lane < NL) ? trans[i * NL + lane] : 0.f;
    float endv = (lane < NL) ? endt[lane] : 0.f;
    float score = (lane < NL) ? start[lane] + em[(size_t)b * NL + lane] : -1e30f;

    for (int t = 1; t < len; ++t) {
        float emv = (lane < NL) ? em[((size_t)t * NB + b) * NL + lane] : 0.f;
        float sv[NL];
        #pragma unroll
        for (int i = 0; i < NL; ++i) sv[i] = __shfl(score, i) + tcol[i];
        float m = sv[0];
        #pragma unroll
        for (int i = 1; i < NL; ++i) m = fmaxf(m, sv[i]);
        float sum = 0.f;
        #pragma unroll
        for (int i = 0; i < NL; ++i) sum += __expf(sv[i] - m);
        float nxt = m + __logf(sum) + emv;
        if (lane < NL) score = nxt;
    }
    float v = (lane < NL) ? score + endv : -1e30f;
    float m = -1e30f;
    float sv[NL];
    #pragma unroll
    for (int i = 0; i < NL; ++i) { sv[i] = __shfl(v, i); m = fmaxf(m, sv[i]); }
    float sum = 0.f;
    #pragma unroll
    for (int i = 0; i < NL; ++i) sum += __expf(sv[i] - m);
    float logZ = m + __logf(sum);
    if (lane == 0) diff[b] = logZ - numbuf[b];
}

// ---------------- K7: mean over batch -> d_out ------------------------------
__global__ void final_k(const float* __restrict__ diff, float* __restrict__ out) {
    float v = diff[threadIdx.x];
    #pragma unroll
    for (int off = 32; off > 0; off >>= 1) v += __shfl_down(v, off);
    if (threadIdx.x == 0) out[0] = v * (1.0f / NB);
}

extern "C" void kernel_launch(void* const* d_in, const int* in_sizes, int n_in,
                              void* d_out, int out_size, void* d_ws, size_t ws_size,
                              hipStream_t stream) {
    const float* emb   = (const float*)d_in[0];
    const float* Wihf  = (const float*)d_in[1];
    const float* Whhf  = (const float*)d_in[2];
    const float* bf    = (const float*)d_in[3];
    const float* Wihb  = (const float*)d_in[4];
    const float* Whhb  = (const float*)d_in[5];
    const float* bb    = (const float*)d_in[6];
    const float* Wlin  = (const float*)d_in[7];
    const float* blin  = (const float*)d_in[8];
    const float* start = (const float*)d_in[9];
    const float* endt  = (const float*)d_in[10];
    const float* trans = (const float*)d_in[11];
    const int*   mask  = (const int*)d_in[12];
    const int*   labels= (const int*)d_in[13];

    char* ws = (char*)d_ws;
    ushort_t* xbf   = (ushort_t*)(ws + 0);                     // 50,331,648
    ushort_t* wcat  = (ushort_t*)(ws + 50331648);              //  3,145,728
    uchar_t*  whh8  = (uchar_t*) (ws + 53477376);              //    524,288
    float*    bias  = (float*)   (ws + 54001664);              //      8,192
    ushort_t* xg    = (ushort_t*)(ws + 54009856);              // 134,217,728
    uchar_t*  hh8   = (uchar_t*) (ws + 188227584);             // 16,777,216
    float*    em    = (float*)   (ws + 205004800);             //  1,179,648
    float*    numb  = (float*)   (ws + 206184448);             //        256
    float*    diff  = (float*)   (ws + 206184704);             //        256

    conv_x<<<NT * NB * (NE / 4) / 256, 256, 0, stream>>>(emb, xbf);
    conv_w<<<(NCC * NE + NCC * NH / 2 + NCC) / 256, 256, 0, stream>>>(
        Wihf, Wihb, Whhf, Whhb, bf, bb, wcat, whh8, bias);
    gemm_xg<<<dim3(NCC / 128, NT * NB / 128), 256, 0, stream>>>(xbf, wcat, bias, xg);
    lstm_k<<<8, 512, 0, stream>>>(xg, whh8, hh8);
    em_k<<<NT, 576, 0, stream>>>(hh8, Wlin, blin, em);
    num_k<<<NB, 64, 0, stream>>>(em, mask, labels, start, endt, trans, numb);
    crf_k<<<NB, 64, 0, stream>>>(em, mask, start, endt, trans, numb, diff);
    final_k<<<1, 64, 0, stream>>>(diff, (float*)d_out);
}

// Round 5
// 1817.139 us; speedup vs baseline: 1.5609x; 1.0022x over previous
//
#include <hip/hip_runtime.h>
#include <hip/hip_bf16.h>
#include <cstdint>
#include <cstddef>

// B=64 T=512 E=768 H=256 L=9.  BiLSTM + linear + CRF loglik (scalar out).
// R9b (de-risked resubmit of R9; two container failures on the R9 binary):
//  - __launch_bounds__(512,2) restored to R8's proven spec (was (512,1)).
//  - rolled step loop (no macro x2 unroll): prefetch xg into xn, compute
//    with xa, register-copy xa=xn (8 v_mov_b64/step, noise).
// Retained R9 optimizations over R8:
//  - packed-f32 (v_pk_*) gate math: 4 float2 pairs instead of 8 scalar gates;
//    cvt_pk_fp8 converts 2 h per op.
//  - k-permuted h layout (pos = w*32+q*8+mt): each thread's 8 h bytes are
//    contiguous -> ONE ds_write_b64 (was 8 ds_write_b8, 1M bank conflicts).
//    W_hh columns (conv_w) and W_lin columns (em_k) carry the inverse perm.
//  - xg register prefetch: next step's 8x8B loads issue before MFMA/epilogue.

typedef __attribute__((ext_vector_type(8))) short short8;
typedef __attribute__((ext_vector_type(4))) float floatx4;
typedef __attribute__((ext_vector_type(2))) float floatx2;
typedef __attribute__((ext_vector_type(2))) float f32x2;
typedef __attribute__((ext_vector_type(8))) int v8i;
typedef unsigned short ushort_t;
typedef unsigned char uchar_t;
typedef unsigned int uint_t;
typedef unsigned long long ull_t;

#define NB   64
#define NT   512
#define NE   768
#define NH   256
#define NL   9
#define NG   1024   // 4*H
#define NCC  2048   // both dirs' gates
#define HPAD 272    // LDS h row stride (bytes, fp8): 17x16B -> 16B-aligned rows

// storage pos p <-> hidden unit hu (within each 32-block):
//   hu_of_pos(p) = (p&~31) | ((p&7)<<2) | ((p>>3)&3)
//   pos_of_hu(h) = (h&~31) | ((h&3)<<3) | ((h&31)>>2)

__device__ inline float asf(uint_t u) {
    union { uint_t i; float f; } v; v.i = u; return v.f;
}
__device__ inline ushort_t f2b(float f) {
    union { float f; uint_t i; } v; v.f = f;
    uint_t r = (v.i + 0x7FFFu + ((v.i >> 16) & 1u)) >> 16;
    return (ushort_t)r;
}

// ---------------- K1: embeddings (B,T,E) f32 -> xbf (T,B,E) bf16 ------------
__global__ void conv_x(const float* __restrict__ emb, ushort_t* __restrict__ xbf) {
    int id = blockIdx.x * blockDim.x + threadIdx.x;      // over T*B*(E/4)
    int t  = id / (NB * (NE / 4));
    int rm = id - t * (NB * (NE / 4));
    int b  = rm / (NE / 4);
    int e4 = rm - b * (NE / 4);
    const float4 v = *(const float4*)(emb + ((size_t)b * NT + t) * NE + e4 * 4);
    ushort_t o[4] = { f2b(v.x), f2b(v.y), f2b(v.z), f2b(v.w) };
    *(uint2*)(xbf + ((size_t)t * NB + b) * NE + e4 * 4) = *(const uint2*)o;
}

// ---------------- K1b: weights. Row interleave: row' = d*1024 + hu*4 + gate -
// Rows prescaled: i,f,o by log2(e); g by 2*log2(e)  (log2-domain gates).
// whh8 column k holds W column hu_of_pos(k)  (h stored in pos-order).
__global__ void conv_w(const float* __restrict__ Wihf, const float* __restrict__ Wihb,
                       const float* __restrict__ Whhf, const float* __restrict__ Whhb,
                       const float* __restrict__ bf,   const float* __restrict__ bb,
                       ushort_t* __restrict__ wcat, uchar_t* __restrict__ whh8,
                       float* __restrict__ bias) {
    int idx = blockIdx.x * blockDim.x + threadIdx.x;
    const int NW1 = NCC * NE;            // 1572864
    const int NW2 = NCC * NH / 2;        // 262144 fp8 pairs
    const float SC1 = 1.4426950408889634f;
    const float SC2 = 2.8853900817779268f;
    if (idx < NW1) {
        int rowp = idx / NE, col = idx - rowp * NE;
        int d = rowp >> 10, rr = rowp & 1023;
        int hu = rr >> 2, gate = rr & 3;
        float sc = (gate == 2) ? SC2 : SC1;
        const float* W = d ? Wihb : Wihf;
        wcat[idx] = f2b(W[(size_t)(gate * NH + hu) * NE + col] * sc);
    } else if (idx < NW1 + NW2) {
        int j = idx - NW1;
        int rowp = j >> 7, kp = (j & 127) * 2;
        int d = rowp >> 10, rr = rowp & 1023;
        int hu = rr >> 2, gate = rr & 3;
        float sc = (gate == 2) ? SC2 : SC1;
        const float* W = d ? Whhb : Whhf;
        int c0 = (kp & ~31) | ((kp & 7) << 2) | ((kp >> 3) & 3);
        int k1 = kp + 1;
        int c1 = (k1 & ~31) | ((k1 & 7) << 2) | ((k1 >> 3) & 3);
        float f0 = W[(size_t)(gate * NH + hu) * NH + c0] * sc;
        float f1 = W[(size_t)(gate * NH + hu) * NH + c1] * sc;
        uint_t pk = __builtin_amdgcn_cvt_pk_fp8_f32(f0, f1, 0, false);
        *(ushort_t*)(whh8 + (size_t)rowp * NH + kp) = (ushort_t)(pk & 0xFFFF);
    } else if (idx < NW1 + NW2 + NCC) {
        int rowp = idx - NW1 - NW2;
        int d = rowp >> 10, rr = rowp & 1023;
        int hu = rr >> 2, gate = rr & 3;
        float sc = (gate == 2) ? SC2 : SC1;
        bias[rowp] = (d ? bb : bf)[gate * NH + hu] * sc;
    }
}

// ---------------- K2: xg = xbf(32768x768) @ wcat^T(2048x768) + bias ---------
__global__ __launch_bounds__(256) void gemm_xg(const ushort_t* __restrict__ A,
                                               const ushort_t* __restrict__ W,
                                               const float* __restrict__ bias,
                                               ushort_t* __restrict__ C) {
    __shared__ ushort_t As[128 * 72];
    __shared__ ushort_t Bs[128 * 72];
    const int tid = threadIdx.x;
    const int wave = tid >> 6, lane = tid & 63;
    const int q = lane >> 4, m16 = lane & 15;
    const int wm = wave & 1, wn = wave >> 1;
    const int m0 = blockIdx.y * 128, n0 = blockIdx.x * 128;

    floatx4 acc[4][4];
    #pragma unroll
    for (int i = 0; i < 4; ++i)
        #pragma unroll
        for (int j = 0; j < 4; ++j) acc[i][j] = (floatx4){0.f, 0.f, 0.f, 0.f};

    for (int kt = 0; kt < NE / 64; ++kt) {
        __syncthreads();
        #pragma unroll
        for (int it = 0; it < 4; ++it) {
            int chunk = tid + it * 256;         // 0..1023
            int row = chunk >> 3, kc = chunk & 7;
            *(uint4*)(&As[row * 72 + kc * 8]) =
                *(const uint4*)(A + (size_t)(m0 + row) * NE + kt * 64 + kc * 8);
            *(uint4*)(&Bs[row * 72 + kc * 8]) =
                *(const uint4*)(W + (size_t)(n0 + row) * NE + kt * 64 + kc * 8);
        }
        __syncthreads();
        #pragma unroll
        for (int ks = 0; ks < 2; ++ks) {
            short8 af[4], bfr[4];
            #pragma unroll
            for (int mt = 0; mt < 4; ++mt)
                af[mt] = *(const short8*)(&As[(wm * 64 + mt * 16 + m16) * 72 + ks * 32 + q * 8]);
            #pragma unroll
            for (int nt = 0; nt < 4; ++nt)
                bfr[nt] = *(const short8*)(&Bs[(wn * 64 + nt * 16 + m16) * 72 + ks * 32 + q * 8]);
            #pragma unroll
            for (int mt = 0; mt < 4; ++mt)
                #pragma unroll
                for (int nt = 0; nt < 4; ++nt)
                    acc[mt][nt] = __builtin_amdgcn_mfma_f32_16x16x32_bf16(
                        af[mt], bfr[nt], acc[mt][nt], 0, 0, 0);
        }
    }
    float bcol[4];
    #pragma unroll
    for (int nt = 0; nt < 4; ++nt) bcol[nt] = bias[n0 + wn * 64 + nt * 16 + m16];
    #pragma unroll
    for (int mt = 0; mt < 4; ++mt)
        #pragma unroll
        for (int nt = 0; nt < 4; ++nt) {
            int gn = n0 + wn * 64 + nt * 16 + m16;
            #pragma unroll
            for (int r = 0; r < 4; ++r) {
                int gm = m0 + wm * 64 + mt * 16 + q * 4 + r;
                C[(size_t)gm * NCC + gn] = f2b(acc[mt][nt][r] + bcol[nt]);
            }
        }
}

// ---------------- packed log2-domain LSTM gate pair -------------------------
// Two hu's full gate math in float2 lanes (v_pk_* f32).  Inputs prescaled:
// pi,pf,po = log2e*preact ; pg = 2*log2e*preact.  Returns 2 fp8 h bytes.
__device__ inline f32x2 exp2v(f32x2 x) {
    return (f32x2){__builtin_amdgcn_exp2f(x.x), __builtin_amdgcn_exp2f(x.y)};
}
__device__ inline f32x2 rcpv(f32x2 x) {
    return (f32x2){__builtin_amdgcn_rcpf(x.x), __builtin_amdgcn_rcpf(x.y)};
}
__device__ inline f32x2 maxv(f32x2 a, float b) {
    return (f32x2){fmaxf(a.x, b), fmaxf(a.y, b)};
}
__device__ inline f32x2 minv(f32x2 a, float b) {
    return (f32x2){fminf(a.x, b), fminf(a.y, b)};
}
__device__ inline uint_t lstm_gate2(floatx4 a0, floatx4 a1, ull_t x0, ull_t x1,
                                    f32x2& cc) {
    uint_t l0 = (uint_t)x0, h0 = (uint_t)(x0 >> 32);
    uint_t l1 = (uint_t)x1, h1 = (uint_t)(x1 >> 32);
    f32x2 pi = (f32x2){a0[0], a1[0]} + (f32x2){asf(l0 << 16), asf(l1 << 16)};
    f32x2 pf = (f32x2){a0[1], a1[1]} + (f32x2){asf(l0 & 0xffff0000u), asf(l1 & 0xffff0000u)};
    f32x2 pg = (f32x2){a0[2], a1[2]} + (f32x2){asf(h0 << 16), asf(h1 << 16)};
    f32x2 po = (f32x2){a0[3], a1[3]} + (f32x2){asf(h0 & 0xffff0000u), asf(h1 & 0xffff0000u)};
    f32x2 ei = exp2v(-maxv(pi, -40.f));     // e^-i
    f32x2 ef = exp2v(-maxv(pf, -40.f));     // e^-f
    f32x2 eo = exp2v(-maxv(po, -40.f));     // e^-o
    f32x2 ug = exp2v( minv(pg,  40.f));     // e^{2g}
    f32x2 A  = 1.f + ei, Bv = 1.f + ug, C = 1.f + ef;
    f32x2 AB = A * Bv;
    f32x2 num = (Bv - 2.f) * C + cc * AB;
    f32x2 cn = num * rcpv(C * AB);
    cc = cn;
    f32x2 uc = exp2v(minv(cn * 2.8853900817779268f, 40.f));
    f32x2 hh = (uc - 1.f) * rcpv((uc + 1.f) * (1.f + eo));
    return __builtin_amdgcn_cvt_pk_fp8_f32(hh.x, hh.y, 0, false) & 0xFFFFu;
}

// ---------------- K3: recurrence, 8 WGs = 2 dirs x 4 batch-groups -----------
// 512 threads = 8 waves; wave w owns gate rows' [w*128, w*128+128).  fp8
// weights in AGPRs, MX-scaled MFMA K=128 unit scales.  h LDS double buffer in
// pos-order (thread's 8 bytes contiguous -> 1 ds_write_b64).  xg prefetched
// one step ahead into registers (rolled loop, register copy).
__global__ __launch_bounds__(512, 2) void lstm_k(const ushort_t* __restrict__ xg,
                                                 const uchar_t* __restrict__ whh8,
                                                 uchar_t* __restrict__ hhist8) {
    const int d  = blockIdx.x >> 2;
    const int bg = blockIdx.x & 3;
    const int tid = threadIdx.x;
    const int w = tid >> 6, lane = tid & 63;
    const int q = lane >> 4, m16 = lane & 15;
    const int bl = bg * 16 + m16;               // this lane's batch (global)

    __shared__ uchar_t hb8[2][16 * HPAD];       // fp8 h (pos-order), [batch][pos]
    for (int i = tid; i < 16 * HPAD; i += 512) hb8[0][i] = 0;

    // Weight A-frags: rows' w*128+mt*16+m16, k = kh*128 + q*32 (32B each).
    const uchar_t* wp = whh8 + (size_t)(d * NG + w * 128) * NH;
    v8i wreg[8][2];
    #pragma unroll
    for (int mt = 0; mt < 8; ++mt)
        #pragma unroll
        for (int kh = 0; kh < 2; ++kh)
            wreg[mt][kh] = *(const v8i*)(wp + (size_t)(mt * 16 + m16) * NH + kh * 128 + q * 32);
    #pragma unroll
    for (int mt = 0; mt < 8; ++mt)
        #pragma unroll
        for (int kh = 0; kh < 2; ++kh)
            asm volatile("" : "+a"(wreg[mt][kh]));   // pin in AGPR class

    f32x2 c2[4];
    #pragma unroll
    for (int i = 0; i < 4; ++i) c2[i] = (f32x2){0.f, 0.f};
    __syncthreads();

    const int scl = 0x7f7f7f7f;                 // e8m0 scale = 1.0 in all bytes
    const ushort_t* xb_ = xg + (size_t)d * NG + w * 128 + q * 4;

    ull_t xa[8], xn[8];
    {
        const int t0 = d ? (NT - 1) : 0;
        const ushort_t* xp0 = xb_ + (size_t)(t0 * NB + bl) * NCC;
        #pragma unroll
        for (int mt = 0; mt < 8; ++mt) xa[mt] = *(const ull_t*)(xp0 + mt * 16);
    }

    #pragma unroll 1
    for (int s = 0; s < NT; ++s) {
        const int t = d ? (NT - 1 - s) : s;

        // Prefetch next step's xg into xn (lands under MFMA + epilogue).
        if (s + 1 < NT) {
            const int tn = d ? (NT - 2 - s) : (s + 1);
            const ushort_t* xpn = xb_ + (size_t)(tn * NB + bl) * NCC;
            #pragma unroll
            for (int mt = 0; mt < 8; ++mt) xn[mt] = *(const ull_t*)(xpn + mt * 16);
        }

        // B-frags: h_prev fp8 (pos-order) from LDS, 32B per k-half.
        const uchar_t* hrow = &hb8[s & 1][m16 * HPAD];
        v8i hf0 = *(const v8i*)(hrow + q * 32);
        v8i hf1 = *(const v8i*)(hrow + 128 + q * 32);

        floatx4 acc[8];
        #pragma unroll
        for (int mt = 0; mt < 8; ++mt) acc[mt] = (floatx4){0.f, 0.f, 0.f, 0.f};
        #pragma unroll
        for (int mt = 0; mt < 8; ++mt)
            acc[mt] = __builtin_amdgcn_mfma_scale_f32_16x16x128_f8f6f4(
                wreg[mt][0], hf0, acc[mt], 0, 0, 0, scl, 0, scl);
        #pragma unroll
        for (int mt = 0; mt < 8; ++mt)
            acc[mt] = __builtin_amdgcn_mfma_scale_f32_16x16x128_f8f6f4(
                wreg[mt][1], hf1, acc[mt], 0, 0, 0, scl, 0, scl);

        // Epilogue: packed pairs; thread's 8 h bytes contiguous at pos
        // w*32 + q*8 + mt  ->  one ds_write_b64.
        uint_t u0 = lstm_gate2(acc[0], acc[1], xa[0], xa[1], c2[0]);
        uint_t u1 = lstm_gate2(acc[2], acc[3], xa[2], xa[3], c2[1]);
        uint_t u2 = lstm_gate2(acc[4], acc[5], xa[4], xa[5], c2[2]);
        uint_t u3 = lstm_gate2(acc[6], acc[7], xa[6], xa[7], c2[3]);
        ull_t hv = (ull_t)u0 | ((ull_t)u1 << 16) | ((ull_t)u2 << 32) | ((ull_t)u3 << 48);
        *(ull_t*)(&hb8[(s + 1) & 1][m16 * HPAD + w * 32 + q * 8]) = hv;

        // Rotate prefetched xg into place.
        #pragma unroll
        for (int mt = 0; mt < 8; ++mt) xa[mt] = xn[mt];

        __syncthreads();
        // Coalesced fp8 h-history write: 4KB per step per WG, 8B/thread.
        {
            int b = tid >> 5, off = (tid & 31) * 8;
            ull_t v = *(const ull_t*)(&hb8[(s + 1) & 1][b * HPAD + off]);
            *(ull_t*)(hhist8 + ((size_t)(d * NT + t) * NB + bg * 16 + b) * NH + off) = v;
        }
    }
}

// ---------------- K4: em[t,b,l] = feats . W_lin[l] + b_lin ------------------
// h history is in pos-order; W_lin columns loaded with pos_of_hu permutation.
__global__ void em_k(const uchar_t* __restrict__ hhist8, const float* __restrict__ Wlin,
                     const float* __restrict__ blin, float* __restrict__ em) {
    const int t = blockIdx.x;
    const int tid = threadIdx.x;          // 576 threads
    __shared__ float Ws[NL * 520];
    for (int idx = tid; idx < NL * 2 * NH; idx += 576) {
        int l = idx >> 9, k = idx & 511;
        int kp = (k & ~31) | ((k & 3) << 3) | ((k & 31) >> 2);   // pos_of_hu
        Ws[l * 520 + kp] = Wlin[l * 2 * NH + k];
    }
    __syncthreads();
    const int b = tid / NL, l = tid - b * NL;
    const uchar_t* hf = hhist8 + ((size_t)t * NB + b) * NH;
    const uchar_t* hb = hhist8 + ((size_t)(NT + t) * NB + b) * NH;
    float acc = blin[l];
    #pragma unroll 4
    for (int kc = 0; kc < NH / 4; ++kc) {
        uint_t u = *(const uint_t*)(hf + kc * 4);
        floatx2 p0 = __builtin_amdgcn_cvt_pk_f32_fp8(u, false);
        floatx2 p1 = __builtin_amdgcn_cvt_pk_f32_fp8(u, true);
        acc += p0.x * Ws[l * 520 + kc * 4]     + p0.y * Ws[l * 520 + kc * 4 + 1]
             + p1.x * Ws[l * 520 + kc * 4 + 2] + p1.y * Ws[l * 520 + kc * 4 + 3];
    }
    #pragma unroll 4
    for (int kc = 0; kc < NH / 4; ++kc) {
        uint_t u = *(const uint_t*)(hb + kc * 4);
        floatx2 p0 = __builtin_amdgcn_cvt_pk_f32_fp8(u, false);
        floatx2 p1 = __builtin_amdgcn_cvt_pk_f32_fp8(u, true);
        acc += p0.x * Ws[l * 520 + NH + kc * 4]     + p0.y * Ws[l * 520 + NH + kc * 4 + 1]
             + p1.x * Ws[l * 520 + NH + kc * 4 + 2] + p1.y * Ws[l * 520 + NH + kc * 4 + 3];
    }
    em[((size_t)t * NB + b) * NL + l] = acc;
}

// ---------------- K5: CRF numerator per batch (parallel over t) -------------
__global__ void num_k(const float* __restrict__ em, const int* __restrict__ mask,
                      const int* __restrict__ labels, const float* __restrict__ start,
                      const float* __restrict__ endt, const float* __restrict__ trans,
                      float* __restrict__ numbuf) {
    const int b = blockIdx.x;       // 64 blocks x 64 threads (1 wave)
    const int lane = threadIdx.x;
    int cntm = 0;
    for (int t = lane; t < NT; t += 64) cntm += (mask[b * NT + t] != 0);
    #pragma unroll
    for (int off = 32; off > 0; off >>= 1) cntm += __shfl_down(cntm, off);
    const int len = __shfl(cntm, 0);

    float part = 0.f;
    for (int t = lane; t < NT; t += 64) {
        if (t >= 1 && t < len) {
            int tp = labels[b * NT + t - 1];
            int tg = labels[b * NT + t];
            part += trans[tp * NL + tg] + em[((size_t)t * NB + b) * NL + tg];
        }
    }
    #pragma unroll
    for (int off = 32; off > 0; off >>= 1) part += __shfl_down(part, off);
    if (lane == 0) {
        int tag0 = labels[b * NT];
        numbuf[b] = part + start[tag0] + em[(size_t)b * NL + tag0]
                  + endt[labels[b * NT + len - 1]];
    }
}

// ---------------- K6: CRF forward (logZ), diff = logZ - num -----------------
__global__ void crf_k(const float* __restrict__ em, const int* __restrict__ mask,
                      const float* __restrict__ start, const float* __restrict__ endt,
                      const float* __restrict__ trans, const float* __restrict__ numbuf,
                      float* __restrict__ diff) {
    const int b = blockIdx.x;
    const int lane = threadIdx.x;       // 64 threads = 1 wave
    int cnt = 0;
    for (int t = lane; t < NT; t += 64) cnt += (mask[b * NT + t] != 0);
    #pragma unroll
    for (int off = 32; off > 0; off >>= 1) cnt += __shfl_down(cnt, off);
    const int len = __shfl(cnt, 0);

    float tcol[NL];
    #pragma unroll
    for (int i = 0; i < NL; ++i) tcol[i] = (lane < NL) ? trans[i * NL + lane] : 0.f;
    float endv = (lane < NL) ? endt[lane] : 0.f;
    float score = (lane < NL) ? start[lane] + em[(size_t)b * NL + lane] : -1e30f;

    for (int t = 1; t < len; ++t) {
        float emv = (lane < NL) ? em[((size_t)t * NB + b) * NL + lane] : 0.f;
        float sv[NL];
        #pragma unroll
        for (int i = 0; i < NL; ++i) sv[i] = __shfl(score, i) + tcol[i];
        float m = sv[0];
        #pragma unroll
        for (int i = 1; i < NL; ++i) m = fmaxf(m, sv[i]);
        float sum = 0.f;
        #pragma unroll
        for (int i = 0; i < NL; ++i) sum += __expf(sv[i] - m);
        float nxt = m + __logf(sum) + emv;
        if (lane < NL) score = nxt;
    }
    float v = (lane < NL) ? score + endv : -1e30f;
    float m = -1e30f;
    float sv[NL];
    #pragma unroll
    for (int i = 0; i < NL; ++i) { sv[i] = __shfl(v, i); m = fmaxf(m, sv[i]); }
    float sum = 0.f;
    #pragma unroll
    for (int i = 0; i < NL; ++i) sum += __expf(sv[i] - m);
    float logZ = m + __logf(sum);
    if (lane == 0) diff[b] = logZ - numbuf[b];
}

// ---------------- K7: mean over batch -> d_out ------------------------------
__global__ void final_k(const float* __restrict__ diff, float* __restrict__ out) {
    float v = diff[threadIdx.x];
    #pragma unroll
    for (int off = 32; off > 0; off >>= 1) v += __shfl_down(v, off);
    if (threadIdx.x == 0) out[0] = v * (1.0f / NB);
}

extern "C" void kernel_launch(void* const* d_in, const int* in_sizes, int n_in,
                              void* d_out, int out_size, void* d_ws, size_t ws_size,
                              hipStream_t stream) {
    const float* emb   = (const float*)d_in[0];
    const float* Wihf  = (const float*)d_in[1];
    const float* Whhf  = (const float*)d_in[2];
    const float* bf    = (const float*)d_in[3];
    const float* Wihb  = (const float*)d_in[4];
    const float* Whhb  = (const float*)d_in[5];
    const float* bb    = (const float*)d_in[6];
    const float* Wlin  = (const float*)d_in[7];
    const float* blin  = (const float*)d_in[8];
    const float* start = (const float*)d_in[9];
    const float* endt  = (const float*)d_in[10];
    const float* trans = (const float*)d_in[11];
    const int*   mask  = (const int*)d_in[12];
    const int*   labels= (const int*)d_in[13];

    char* ws = (char*)d_ws;
    ushort_t* xbf   = (ushort_t*)(ws + 0);                     // 50,331,648
    ushort_t* wcat  = (ushort_t*)(ws + 50331648);              //  3,145,728
    uchar_t*  whh8  = (uchar_t*) (ws + 53477376);              //    524,288
    float*    bias  = (float*)   (ws + 54001664);              //      8,192
    ushort_t* xg    = (ushort_t*)(ws + 54009856);              // 134,217,728
    uchar_t*  hh8   = (uchar_t*) (ws + 188227584);             // 16,777,216
    float*    em    = (float*)   (ws + 205004800);             //  1,179,648
    float*    numb  = (float*)   (ws + 206184448);             //        256
    float*    diff  = (float*)   (ws + 206184704);             //        256

    conv_x<<<NT * NB * (NE / 4) / 256, 256, 0, stream>>>(emb, xbf);
    conv_w<<<(NCC * NE + NCC * NH / 2 + NCC) / 256, 256, 0, stream>>>(
        Wihf, Wihb, Whhf, Whhb, bf, bb, wcat, whh8, bias);
    gemm_xg<<<dim3(NCC / 128, NT * NB / 128), 256, 0, stream>>>(xbf, wcat, bias, xg);
    lstm_k<<<8, 512, 0, stream>>>(xg, whh8, hh8);
    em_k<<<NT, 576, 0, stream>>>(hh8, Wlin, blin, em);
    num_k<<<NB, 64, 0, stream>>>(em, mask, labels, start, endt, trans, numb);
    crf_k<<<NB, 64, 0, stream>>>(em, mask, start, endt, trans, numb, diff);
    final_k<<<1, 64, 0, stream>>>(diff, (float*)d_out);
}

// Round 7
// 1121.287 us; speedup vs baseline: 2.5295x; 1.6206x over previous
//
#include <hip/hip_runtime.h>
#include <hip/hip_bf16.h>
#include <cstdint>
#include <cstddef>

// B=64 T=512 E=768 H=256 L=9.  BiLSTM + linear + CRF loglik (scalar out).
// R10b: R10 with the one-line compile fix (flat LDS zero-init).
// Batch-split recurrence: batches are INDEPENDENT in the recurrence, so
// 32 WGs = 2 dir x 16 bg x 4 batches need zero inter-WG sync (R7's failure
// was splitting hidden units, which needs per-step exchange).  Weights
// replicated per WG.  Measured bottleneck was epilogue transcendental
// throughput (~16cy/wave64 v_exp, 56/thread); lanes=batch meant exec-mask
// couldn't cut wave time.  Fix: in-LDS acc transpose -- valid lanes (m16<4)
// store gate-quads to a swizzled 16KB buffer, barrier, all 64 lanes read
// back (hu-pair, batch) assignments -> 1 gate2/thread (was 4).  xg: one 16B
// load/thread.  h-write: one ds_write_b16.  Natural hu order (perms gone).

typedef __attribute__((ext_vector_type(8))) short short8;
typedef __attribute__((ext_vector_type(4))) float floatx4;
typedef __attribute__((ext_vector_type(2))) float floatx2;
typedef __attribute__((ext_vector_type(2))) float f32x2;
typedef __attribute__((ext_vector_type(8))) int v8i;
typedef unsigned short ushort_t;
typedef unsigned char uchar_t;
typedef unsigned int uint_t;
typedef unsigned long long ull_t;

#define NB   64
#define NT   512
#define NE   768
#define NH   256
#define NL   9
#define NG   1024   // 4*H
#define NCC  2048   // both dirs' gates
#define HPAD 272    // LDS h row stride (bytes, fp8)

__device__ inline float asf(uint_t u) {
    union { uint_t i; float f; } v; v.i = u; return v.f;
}
__device__ inline ushort_t f2b(float f) {
    union { float f; uint_t i; } v; v.f = f;
    uint_t r = (v.i + 0x7FFFu + ((v.i >> 16) & 1u)) >> 16;
    return (ushort_t)r;
}

// ---------------- K1: embeddings (B,T,E) f32 -> xbf (T,B,E) bf16 ------------
__global__ void conv_x(const float* __restrict__ emb, ushort_t* __restrict__ xbf) {
    int id = blockIdx.x * blockDim.x + threadIdx.x;      // over T*B*(E/4)
    int t  = id / (NB * (NE / 4));
    int rm = id - t * (NB * (NE / 4));
    int b  = rm / (NE / 4);
    int e4 = rm - b * (NE / 4);
    const float4 v = *(const float4*)(emb + ((size_t)b * NT + t) * NE + e4 * 4);
    ushort_t o[4] = { f2b(v.x), f2b(v.y), f2b(v.z), f2b(v.w) };
    *(uint2*)(xbf + ((size_t)t * NB + b) * NE + e4 * 4) = *(const uint2*)o;
}

// ---------------- K1b: weights. Row interleave: row' = d*1024 + hu*4 + gate -
// Rows prescaled: i,f,o by log2(e); g by 2*log2(e)  (log2-domain gates).
__global__ void conv_w(const float* __restrict__ Wihf, const float* __restrict__ Wihb,
                       const float* __restrict__ Whhf, const float* __restrict__ Whhb,
                       const float* __restrict__ bf,   const float* __restrict__ bb,
                       ushort_t* __restrict__ wcat, uchar_t* __restrict__ whh8,
                       float* __restrict__ bias) {
    int idx = blockIdx.x * blockDim.x + threadIdx.x;
    const int NW1 = NCC * NE;            // 1572864
    const int NW2 = NCC * NH / 2;        // 262144 fp8 pairs
    const float SC1 = 1.4426950408889634f;
    const float SC2 = 2.8853900817779268f;
    if (idx < NW1) {
        int rowp = idx / NE, col = idx - rowp * NE;
        int d = rowp >> 10, rr = rowp & 1023;
        int hu = rr >> 2, gate = rr & 3;
        float sc = (gate == 2) ? SC2 : SC1;
        const float* W = d ? Wihb : Wihf;
        wcat[idx] = f2b(W[(size_t)(gate * NH + hu) * NE + col] * sc);
    } else if (idx < NW1 + NW2) {
        int j = idx - NW1;
        int rowp = j >> 7, kp = (j & 127) * 2;
        int d = rowp >> 10, rr = rowp & 1023;
        int hu = rr >> 2, gate = rr & 3;
        float sc = (gate == 2) ? SC2 : SC1;
        const float* W = d ? Whhb : Whhf;
        float f0 = W[(size_t)(gate * NH + hu) * NH + kp] * sc;
        float f1 = W[(size_t)(gate * NH + hu) * NH + kp + 1] * sc;
        uint_t pk = __builtin_amdgcn_cvt_pk_fp8_f32(f0, f1, 0, false);
        *(ushort_t*)(whh8 + (size_t)rowp * NH + kp) = (ushort_t)(pk & 0xFFFF);
    } else if (idx < NW1 + NW2 + NCC) {
        int rowp = idx - NW1 - NW2;
        int d = rowp >> 10, rr = rowp & 1023;
        int hu = rr >> 2, gate = rr & 3;
        float sc = (gate == 2) ? SC2 : SC1;
        bias[rowp] = (d ? bb : bf)[gate * NH + hu] * sc;
    }
}

// ---------------- K2: xg = xbf(32768x768) @ wcat^T(2048x768) + bias ---------
__global__ __launch_bounds__(256) void gemm_xg(const ushort_t* __restrict__ A,
                                               const ushort_t* __restrict__ W,
                                               const float* __restrict__ bias,
                                               ushort_t* __restrict__ C) {
    __shared__ ushort_t As[128 * 72];
    __shared__ ushort_t Bs[128 * 72];
    const int tid = threadIdx.x;
    const int wave = tid >> 6, lane = tid & 63;
    const int q = lane >> 4, m16 = lane & 15;
    const int wm = wave & 1, wn = wave >> 1;
    const int m0 = blockIdx.y * 128, n0 = blockIdx.x * 128;

    floatx4 acc[4][4];
    #pragma unroll
    for (int i = 0; i < 4; ++i)
        #pragma unroll
        for (int j = 0; j < 4; ++j) acc[i][j] = (floatx4){0.f, 0.f, 0.f, 0.f};

    for (int kt = 0; kt < NE / 64; ++kt) {
        __syncthreads();
        #pragma unroll
        for (int it = 0; it < 4; ++it) {
            int chunk = tid + it * 256;         // 0..1023
            int row = chunk >> 3, kc = chunk & 7;
            *(uint4*)(&As[row * 72 + kc * 8]) =
                *(const uint4*)(A + (size_t)(m0 + row) * NE + kt * 64 + kc * 8);
            *(uint4*)(&Bs[row * 72 + kc * 8]) =
                *(const uint4*)(W + (size_t)(n0 + row) * NE + kt * 64 + kc * 8);
        }
        __syncthreads();
        #pragma unroll
        for (int ks = 0; ks < 2; ++ks) {
            short8 af[4], bfr[4];
            #pragma unroll
            for (int mt = 0; mt < 4; ++mt)
                af[mt] = *(const short8*)(&As[(wm * 64 + mt * 16 + m16) * 72 + ks * 32 + q * 8]);
            #pragma unroll
            for (int nt = 0; nt < 4; ++nt)
                bfr[nt] = *(const short8*)(&Bs[(wn * 64 + nt * 16 + m16) * 72 + ks * 32 + q * 8]);
            #pragma unroll
            for (int mt = 0; mt < 4; ++mt)
                #pragma unroll
                for (int nt = 0; nt < 4; ++nt)
                    acc[mt][nt] = __builtin_amdgcn_mfma_f32_16x16x32_bf16(
                        af[mt], bfr[nt], acc[mt][nt], 0, 0, 0);
        }
    }
    float bcol[4];
    #pragma unroll
    for (int nt = 0; nt < 4; ++nt) bcol[nt] = bias[n0 + wn * 64 + nt * 16 + m16];
    #pragma unroll
    for (int mt = 0; mt < 4; ++mt)
        #pragma unroll
        for (int nt = 0; nt < 4; ++nt) {
            int gn = n0 + wn * 64 + nt * 16 + m16;
            #pragma unroll
            for (int r = 0; r < 4; ++r) {
                int gm = m0 + wm * 64 + mt * 16 + q * 4 + r;
                C[(size_t)gm * NCC + gn] = f2b(acc[mt][nt][r] + bcol[nt]);
            }
        }
}

// ---------------- packed log2-domain LSTM gate pair (verified R8/R9b) -------
__device__ inline f32x2 exp2v(f32x2 x) {
    return (f32x2){__builtin_amdgcn_exp2f(x.x), __builtin_amdgcn_exp2f(x.y)};
}
__device__ inline f32x2 rcpv(f32x2 x) {
    return (f32x2){__builtin_amdgcn_rcpf(x.x), __builtin_amdgcn_rcpf(x.y)};
}
__device__ inline f32x2 maxv(f32x2 a, float b) {
    return (f32x2){fmaxf(a.x, b), fmaxf(a.y, b)};
}
__device__ inline f32x2 minv(f32x2 a, float b) {
    return (f32x2){fminf(a.x, b), fminf(a.y, b)};
}
__device__ inline uint_t lstm_gate2(floatx4 a0, floatx4 a1, ull_t x0, ull_t x1,
                                    f32x2& cc) {
    uint_t l0 = (uint_t)x0, h0 = (uint_t)(x0 >> 32);
    uint_t l1 = (uint_t)x1, h1 = (uint_t)(x1 >> 32);
    f32x2 pi = (f32x2){a0[0], a1[0]} + (f32x2){asf(l0 << 16), asf(l1 << 16)};
    f32x2 pf = (f32x2){a0[1], a1[1]} + (f32x2){asf(l0 & 0xffff0000u), asf(l1 & 0xffff0000u)};
    f32x2 pg = (f32x2){a0[2], a1[2]} + (f32x2){asf(h0 << 16), asf(h1 << 16)};
    f32x2 po = (f32x2){a0[3], a1[3]} + (f32x2){asf(h0 & 0xffff0000u), asf(h1 & 0xffff0000u)};
    f32x2 ei = exp2v(-maxv(pi, -40.f));     // e^-i
    f32x2 ef = exp2v(-maxv(pf, -40.f));     // e^-f
    f32x2 eo = exp2v(-maxv(po, -40.f));     // e^-o
    f32x2 ug = exp2v( minv(pg,  40.f));     // e^{2g}
    f32x2 A  = 1.f + ei, Bv = 1.f + ug, C = 1.f + ef;
    f32x2 AB = A * Bv;
    f32x2 num = (Bv - 2.f) * C + cc * AB;
    f32x2 cn = num * rcpv(C * AB);
    cc = cn;
    f32x2 uc = exp2v(minv(cn * 2.8853900817779268f, 40.f));
    f32x2 hh = (uc - 1.f) * rcpv((uc + 1.f) * (1.f + eo));
    return __builtin_amdgcn_cvt_pk_fp8_f32(hh.x, hh.y, 0, false) & 0xFFFFu;
}

// acc-transpose LDS offset: slot = hu*64B + batch*16B, XOR-swizzled on bits
// 4-6 by (hu>>1)&7 so writes and reads spread over the 8 16B slots per 128B.
__device__ inline int accT_off(int hu, int b) {
    int h2 = hu >> 1;
    return (hu * 64 + b * 16) ^ ((h2 & 7) << 4);
}

// ---------------- K3: recurrence, 32 WGs = 2 dirs x 16 batch-groups ---------
// 4 batches/WG.  512 threads = 8 waves; wave w computes gate rows
// [w*128, w*128+128) via 16 MFMA (16 cols, 4 valid).  Valid lanes (m16<4)
// store acc quads to accT; after barrier every lane handles (hu pair
// w*32+2p{,+1}, batch lane&3): one gate2, one ds_write_b16, one 16B xg load.
__global__ __launch_bounds__(512, 2) void lstm_k(const ushort_t* __restrict__ xg,
                                                 const uchar_t* __restrict__ whh8,
                                                 uchar_t* __restrict__ hhist8) {
    const int d  = blockIdx.x >> 4;             // direction
    const int bg = blockIdx.x & 15;             // batch group (4 batches)
    const int tid = threadIdx.x;
    const int w = tid >> 6, lane = tid & 63;
    const int q = lane >> 4, m16 = lane & 15;
    const int p    = lane >> 2;                 // hu-pair index 0..15
    const int bloc = lane & 3;                  // local batch 0..3
    const int hu0  = w * 32 + p * 2;            // epilogue hu pair
    const int blg  = bg * 4 + bloc;             // global batch

    __shared__ uchar_t hb8[2][16 * HPAD];       // fp8 h, [local batch][hu]
    __shared__ float   accT[4096];              // 16KB swizzled gate-quads
    for (int i = tid; i < 2 * 16 * HPAD; i += 512) ((uchar_t*)hb8)[i] = 0;

    // Weight A-frags: rows' w*128+mt*16+m16, k = kh*128 + q*32 (32B each).
    const uchar_t* wp = whh8 + (size_t)(d * NG + w * 128) * NH;
    v8i wreg[8][2];
    #pragma unroll
    for (int mt = 0; mt < 8; ++mt)
        #pragma unroll
        for (int kh = 0; kh < 2; ++kh)
            wreg[mt][kh] = *(const v8i*)(wp + (size_t)(mt * 16 + m16) * NH + kh * 128 + q * 32);
    #pragma unroll
    for (int mt = 0; mt < 8; ++mt)
        #pragma unroll
        for (int kh = 0; kh < 2; ++kh)
            asm volatile("" : "+a"(wreg[mt][kh]));   // pin in AGPR class

    f32x2 c2 = (f32x2){0.f, 0.f};
    __syncthreads();

    const int scl = 0x7f7f7f7f;                 // e8m0 scale = 1.0 in all bytes
    // xg: this thread's 8 gate rows (hu0, hu0+1) start at row hu0*4 -> 16B.
    const ushort_t* xb_ = xg + (size_t)d * NG + hu0 * 4;

    uint4 xw, xwn;
    {
        const int t0 = d ? (NT - 1) : 0;
        xw = *(const uint4*)(xb_ + (size_t)(t0 * NB + blg) * NCC);
    }

    #pragma unroll 1
    for (int s = 0; s < NT; ++s) {
        const int t = d ? (NT - 1 - s) : s;

        // Prefetch next step's xg (lands under MFMA + epilogue).
        if (s + 1 < NT) {
            const int tn = d ? (NT - 2 - s) : (s + 1);
            xwn = *(const uint4*)(xb_ + (size_t)(tn * NB + blg) * NCC);
        }

        // B-frags: h_prev fp8 from LDS (rows 4-15 stay zero -> dead cols).
        const uchar_t* hrow = &hb8[s & 1][m16 * HPAD];
        v8i hf0 = *(const v8i*)(hrow + q * 32);
        v8i hf1 = *(const v8i*)(hrow + 128 + q * 32);

        floatx4 acc[8];
        #pragma unroll
        for (int mt = 0; mt < 8; ++mt) acc[mt] = (floatx4){0.f, 0.f, 0.f, 0.f};
        #pragma unroll
        for (int mt = 0; mt < 8; ++mt)
            acc[mt] = __builtin_amdgcn_mfma_scale_f32_16x16x128_f8f6f4(
                wreg[mt][0], hf0, acc[mt], 0, 0, 0, scl, 0, scl);
        #pragma unroll
        for (int mt = 0; mt < 8; ++mt)
            acc[mt] = __builtin_amdgcn_mfma_scale_f32_16x16x128_f8f6f4(
                wreg[mt][1], hf1, acc[mt], 0, 0, 0, scl, 0, scl);

        // acc transpose: valid lanes store their gate-quads.
        if (m16 < 4) {
            #pragma unroll
            for (int mt = 0; mt < 8; ++mt) {
                int hu = w * 32 + mt * 4 + q;
                *(floatx4*)((uchar_t*)accT + accT_off(hu, m16)) = acc[mt];
            }
        }
        __syncthreads();                        // accT complete

        // Every lane: gate math for (hu0, hu0+1) x batch bloc.
        floatx4 a0 = *(const floatx4*)((const uchar_t*)accT + accT_off(hu0,     bloc));
        floatx4 a1 = *(const floatx4*)((const uchar_t*)accT + accT_off(hu0 + 1, bloc));
        ull_t x0 = (ull_t)xw.x | ((ull_t)xw.y << 32);
        ull_t x1 = (ull_t)xw.z | ((ull_t)xw.w << 32);
        uint_t u = lstm_gate2(a0, a1, x0, x1, c2);
        *(ushort_t*)(&hb8[(s + 1) & 1][bloc * HPAD + hu0]) = (ushort_t)u;

        xw = xwn;
        __syncthreads();                        // h(s+1) complete

        // fp8 h-history: 4 batches x 256B = 1KB/step/WG, 8B/thread.
        if (tid < 128) {
            int b_ = tid >> 5, off = (tid & 31) * 8;
            ull_t v = *(const ull_t*)(&hb8[(s + 1) & 1][b_ * HPAD + off]);
            *(ull_t*)(hhist8 + ((size_t)(d * NT + t) * NB + bg * 4 + b_) * NH + off) = v;
        }
    }
}

// ---------------- K4: em[t,b,l] = feats . W_lin[l] + b_lin ------------------
__global__ void em_k(const uchar_t* __restrict__ hhist8, const float* __restrict__ Wlin,
                     const float* __restrict__ blin, float* __restrict__ em) {
    const int t = blockIdx.x;
    const int tid = threadIdx.x;          // 576 threads
    __shared__ float Ws[NL * 520];
    for (int idx = tid; idx < NL * 2 * NH; idx += 576) {
        int l = idx >> 9, k = idx & 511;
        Ws[l * 520 + k] = Wlin[l * 2 * NH + k];
    }
    __syncthreads();
    const int b = tid / NL, l = tid - b * NL;
    const uchar_t* hf = hhist8 + ((size_t)t * NB + b) * NH;
    const uchar_t* hb = hhist8 + ((size_t)(NT + t) * NB + b) * NH;
    float acc = blin[l];
    #pragma unroll 4
    for (int kc = 0; kc < NH / 4; ++kc) {
        uint_t u = *(const uint_t*)(hf + kc * 4);
        floatx2 p0 = __builtin_amdgcn_cvt_pk_f32_fp8(u, false);
        floatx2 p1 = __builtin_amdgcn_cvt_pk_f32_fp8(u, true);
        acc += p0.x * Ws[l * 520 + kc * 4]     + p0.y * Ws[l * 520 + kc * 4 + 1]
             + p1.x * Ws[l * 520 + kc * 4 + 2] + p1.y * Ws[l * 520 + kc * 4 + 3];
    }
    #pragma unroll 4
    for (int kc = 0; kc < NH / 4; ++kc) {
        uint_t u = *(const uint_t*)(hb + kc * 4);
        floatx2 p0 = __builtin_amdgcn_cvt_pk_f32_fp8(u, false);
        floatx2 p1 = __builtin_amdgcn_cvt_pk_f32_fp8(u, true);
        acc += p0.x * Ws[l * 520 + NH + kc * 4]     + p0.y * Ws[l * 520 + NH + kc * 4 + 1]
             + p1.x * Ws[l * 520 + NH + kc * 4 + 2] + p1.y * Ws[l * 520 + NH + kc * 4 + 3];
    }
    em[((size_t)t * NB + b) * NL + l] = acc;
}

// ---------------- K5: CRF numerator per batch (parallel over t) -------------
__global__ void num_k(const float* __restrict__ em, const int* __restrict__ mask,
                      const int* __restrict__ labels, const float* __restrict__ start,
                      const float* __restrict__ endt, const float* __restrict__ trans,
                      float* __restrict__ numbuf) {
    const int b = blockIdx.x;       // 64 blocks x 64 threads (1 wave)
    const int lane = threadIdx.x;
    int cntm = 0;
    for (int t = lane; t < NT; t += 64) cntm += (mask[b * NT + t] != 0);
    #pragma unroll
    for (int off = 32; off > 0; off >>= 1) cntm += __shfl_down(cntm, off);
    const int len = __shfl(cntm, 0);

    float part = 0.f;
    for (int t = lane; t < NT; t += 64) {
        if (t >= 1 && t < len) {
            int tp = labels[b * NT + t - 1];
            int tg = labels[b * NT + t];
            part += trans[tp * NL + tg] + em[((size_t)t * NB + b) * NL + tg];
        }
    }
    #pragma unroll
    for (int off = 32; off > 0; off >>= 1) part += __shfl_down(part, off);
    if (lane == 0) {
        int tag0 = labels[b * NT];
        numbuf[b] = part + start[tag0] + em[(size_t)b * NL + tag0]
                  + endt[labels[b * NT + len - 1]];
    }
}

// ---------------- K6: CRF forward (logZ), diff = logZ - num -----------------
__global__ void crf_k(const float* __restrict__ em, const int* __restrict__ mask,
                      const float* __restrict__ start, const float* __restrict__ endt,
                      const float* __restrict__ trans, const float* __restrict__ numbuf,
                      float* __restrict__ diff) {
    const int b = blockIdx.x;
    const int lane = threadIdx.x;       // 64 threads = 1 wave
    int cnt = 0;
    for (int t = lane; t < NT; t += 64) cnt += (mask[b * NT + t] != 0);
    #pragma unroll
    for (int off = 32; off > 0; off >>= 1) cnt += __shfl_down(cnt, off);
    const int len = __shfl(cnt, 0);

    float tcol[NL];
    #pragma unroll
    for (int i = 0; i < NL; ++i) tcol[i] = (lane < NL) ? trans[i * NL + lane] : 0.f;
    float endv = (lane < NL) ? endt[lane] : 0.f;
    float score = (lane < NL) ? start[lane] + em[(size_t)b * NL + lane] : -1e30f;

    for (int t = 1; t < len; ++t) {
        float emv = (lane < NL) ? em[((size_t)t * NB + b) * NL + lane] : 0.f;
        float sv[NL];
        #pragma unroll
        for (int i = 0; i < NL; ++i) sv[i] = __shfl(score, i) + tcol[i];
        float m = sv[0];
        #pragma unroll
        for (int i = 1; i < NL; ++i) m = fmaxf(m, sv[i]);
        float sum = 0.f;
        #pragma unroll
        for (int i = 0; i < NL; ++i) sum += __expf(sv[i] - m);
        float nxt = m + __logf(sum) + emv;
        if (lane < NL) score = nxt;
    }
    float v = (lane < NL) ? score + endv : -1e30f;
    float m = -1e30f;
    float sv[NL];
    #pragma unroll
    for (int i = 0; i < NL; ++i) { sv[i] = __shfl(v, i); m = fmaxf(m, sv[i]); }
    float sum = 0.f;
    #pragma unroll
    for (int i = 0; i < NL; ++i) sum += __expf(sv[i] - m);
    float logZ = m + __logf(sum);
    if (lane == 0) diff[b] = logZ - numbuf[b];
}

// ---------------- K7: mean over batch -> d_out ------------------------------
__global__ void final_k(const float* __restrict__ diff, float* __restrict__ out) {
    float v = diff[threadIdx.x];
    #pragma unroll
    for (int off = 32; off > 0; off >>= 1) v += __shfl_down(v, off);
    if (threadIdx.x == 0) out[0] = v * (1.0f / NB);
}

extern "C" void kernel_launch(void* const* d_in, const int* in_sizes, int n_in,
                              void* d_out, int out_size, void* d_ws, size_t ws_size,
                              hipStream_t stream) {
    const float* emb   = (const float*)d_in[0];
    const float* Wihf  = (const float*)d_in[1];
    const float* Whhf  = (const float*)d_in[2];
    const float* bf    = (const float*)d_in[3];
    const float* Wihb  = (const float*)d_in[4];
    const float* Whhb  = (const float*)d_in[5];
    const float* bb    = (const float*)d_in[6];
    const float* Wlin  = (const float*)d_in[7];
    const float* blin  = (const float*)d_in[8];
    const float* start = (const float*)d_in[9];
    const float* endt  = (const float*)d_in[10];
    const float* trans = (const float*)d_in[11];
    const int*   mask  = (const int*)d_in[12];
    const int*   labels= (const int*)d_in[13];

    char* ws = (char*)d_ws;
    ushort_t* xbf   = (ushort_t*)(ws + 0);                     // 50,331,648
    ushort_t* wcat  = (ushort_t*)(ws + 50331648);              //  3,145,728
    uchar_t*  whh8  = (uchar_t*) (ws + 53477376);              //    524,288
    float*    bias  = (float*)   (ws + 54001664);              //      8,192
    ushort_t* xg    = (ushort_t*)(ws + 54009856);              // 134,217,728
    uchar_t*  hh8   = (uchar_t*) (ws + 188227584);             // 16,777,216
    float*    em    = (float*)   (ws + 205004800);             //  1,179,648
    float*    numb  = (float*)   (ws + 206184448);             //        256
    float*    diff  = (float*)   (ws + 206184704);             //        256

    conv_x<<<NT * NB * (NE / 4) / 256, 256, 0, stream>>>(emb, xbf);
    conv_w<<<(NCC * NE + NCC * NH / 2 + NCC) / 256, 256, 0, stream>>>(
        Wihf, Wihb, Whhf, Whhb, bf, bb, wcat, whh8, bias);
    gemm_xg<<<dim3(NCC / 128, NT * NB / 128), 256, 0, stream>>>(xbf, wcat, bias, xg);
    lstm_k<<<32, 512, 0, stream>>>(xg, whh8, hh8);
    em_k<<<NT, 576, 0, stream>>>(hh8, Wlin, blin, em);
    num_k<<<NB, 64, 0, stream>>>(em, mask, labels, start, endt, trans, numb);
    crf_k<<<NB, 64, 0, stream>>>(em, mask, start, endt, trans, numb, diff);
    final_k<<<1, 64, 0, stream>>>(diff, (float*)d_out);
}

// Round 8
// 1058.929 us; speedup vs baseline: 2.6785x; 1.0589x over previous
//
#include <hip/hip_runtime.h>
#include <hip/hip_bf16.h>
#include <cstdint>
#include <cstddef>

// B=64 T=512 E=768 H=256 L=9.  BiLSTM + linear + CRF loglik (scalar out).
// R11: push the batch-split one notch: 64 WGs = 2 dir x 32 bg x 2 batches
// (zero inter-WG sync, weights replicated; MFMA per WG is invariant but that
// pipe is idle).  Each thread owns ONE (hu, batch): one scalar log2-gate
// (7 trans, half of R10b's 14), one 8B xg load, one ds_write_b8, one 16B
// accT read.  accT is now 8KB and UNSWIZZLED: per-m-tile writes from the 8
// valid lanes form one contiguous 128B line (conflict-free), reads are
// lane*16 contiguous (conflict-free).

typedef __attribute__((ext_vector_type(8))) short short8;
typedef __attribute__((ext_vector_type(4))) float floatx4;
typedef __attribute__((ext_vector_type(2))) float floatx2;
typedef __attribute__((ext_vector_type(8))) int v8i;
typedef unsigned short ushort_t;
typedef unsigned char uchar_t;
typedef unsigned int uint_t;
typedef unsigned long long ull_t;

#define NB   64
#define NT   512
#define NE   768
#define NH   256
#define NL   9
#define NG   1024   // 4*H
#define NCC  2048   // both dirs' gates
#define HPAD 272    // LDS h row stride (bytes, fp8)

__device__ inline float asf(uint_t u) {
    union { uint_t i; float f; } v; v.i = u; return v.f;
}
__device__ inline ushort_t f2b(float f) {
    union { float f; uint_t i; } v; v.f = f;
    uint_t r = (v.i + 0x7FFFu + ((v.i >> 16) & 1u)) >> 16;
    return (ushort_t)r;
}

// ---------------- K1: embeddings (B,T,E) f32 -> xbf (T,B,E) bf16 ------------
__global__ void conv_x(const float* __restrict__ emb, ushort_t* __restrict__ xbf) {
    int id = blockIdx.x * blockDim.x + threadIdx.x;      // over T*B*(E/4)
    int t  = id / (NB * (NE / 4));
    int rm = id - t * (NB * (NE / 4));
    int b  = rm / (NE / 4);
    int e4 = rm - b * (NE / 4);
    const float4 v = *(const float4*)(emb + ((size_t)b * NT + t) * NE + e4 * 4);
    ushort_t o[4] = { f2b(v.x), f2b(v.y), f2b(v.z), f2b(v.w) };
    *(uint2*)(xbf + ((size_t)t * NB + b) * NE + e4 * 4) = *(const uint2*)o;
}

// ---------------- K1b: weights. Row interleave: row' = d*1024 + hu*4 + gate -
// Rows prescaled: i,f,o by log2(e); g by 2*log2(e)  (log2-domain gates).
__global__ void conv_w(const float* __restrict__ Wihf, const float* __restrict__ Wihb,
                       const float* __restrict__ Whhf, const float* __restrict__ Whhb,
                       const float* __restrict__ bf,   const float* __restrict__ bb,
                       ushort_t* __restrict__ wcat, uchar_t* __restrict__ whh8,
                       float* __restrict__ bias) {
    int idx = blockIdx.x * blockDim.x + threadIdx.x;
    const int NW1 = NCC * NE;            // 1572864
    const int NW2 = NCC * NH / 2;        // 262144 fp8 pairs
    const float SC1 = 1.4426950408889634f;
    const float SC2 = 2.8853900817779268f;
    if (idx < NW1) {
        int rowp = idx / NE, col = idx - rowp * NE;
        int d = rowp >> 10, rr = rowp & 1023;
        int hu = rr >> 2, gate = rr & 3;
        float sc = (gate == 2) ? SC2 : SC1;
        const float* W = d ? Wihb : Wihf;
        wcat[idx] = f2b(W[(size_t)(gate * NH + hu) * NE + col] * sc);
    } else if (idx < NW1 + NW2) {
        int j = idx - NW1;
        int rowp = j >> 7, kp = (j & 127) * 2;
        int d = rowp >> 10, rr = rowp & 1023;
        int hu = rr >> 2, gate = rr & 3;
        float sc = (gate == 2) ? SC2 : SC1;
        const float* W = d ? Whhb : Whhf;
        float f0 = W[(size_t)(gate * NH + hu) * NH + kp] * sc;
        float f1 = W[(size_t)(gate * NH + hu) * NH + kp + 1] * sc;
        uint_t pk = __builtin_amdgcn_cvt_pk_fp8_f32(f0, f1, 0, false);
        *(ushort_t*)(whh8 + (size_t)rowp * NH + kp) = (ushort_t)(pk & 0xFFFF);
    } else if (idx < NW1 + NW2 + NCC) {
        int rowp = idx - NW1 - NW2;
        int d = rowp >> 10, rr = rowp & 1023;
        int hu = rr >> 2, gate = rr & 3;
        float sc = (gate == 2) ? SC2 : SC1;
        bias[rowp] = (d ? bb : bf)[gate * NH + hu] * sc;
    }
}

// ---------------- K2: xg = xbf(32768x768) @ wcat^T(2048x768) + bias ---------
__global__ __launch_bounds__(256) void gemm_xg(const ushort_t* __restrict__ A,
                                               const ushort_t* __restrict__ W,
                                               const float* __restrict__ bias,
                                               ushort_t* __restrict__ C) {
    __shared__ ushort_t As[128 * 72];
    __shared__ ushort_t Bs[128 * 72];
    const int tid = threadIdx.x;
    const int wave = tid >> 6, lane = tid & 63;
    const int q = lane >> 4, m16 = lane & 15;
    const int wm = wave & 1, wn = wave >> 1;
    const int m0 = blockIdx.y * 128, n0 = blockIdx.x * 128;

    floatx4 acc[4][4];
    #pragma unroll
    for (int i = 0; i < 4; ++i)
        #pragma unroll
        for (int j = 0; j < 4; ++j) acc[i][j] = (floatx4){0.f, 0.f, 0.f, 0.f};

    for (int kt = 0; kt < NE / 64; ++kt) {
        __syncthreads();
        #pragma unroll
        for (int it = 0; it < 4; ++it) {
            int chunk = tid + it * 256;         // 0..1023
            int row = chunk >> 3, kc = chunk & 7;
            *(uint4*)(&As[row * 72 + kc * 8]) =
                *(const uint4*)(A + (size_t)(m0 + row) * NE + kt * 64 + kc * 8);
            *(uint4*)(&Bs[row * 72 + kc * 8]) =
                *(const uint4*)(W + (size_t)(n0 + row) * NE + kt * 64 + kc * 8);
        }
        __syncthreads();
        #pragma unroll
        for (int ks = 0; ks < 2; ++ks) {
            short8 af[4], bfr[4];
            #pragma unroll
            for (int mt = 0; mt < 4; ++mt)
                af[mt] = *(const short8*)(&As[(wm * 64 + mt * 16 + m16) * 72 + ks * 32 + q * 8]);
            #pragma unroll
            for (int nt = 0; nt < 4; ++nt)
                bfr[nt] = *(const short8*)(&Bs[(wn * 64 + nt * 16 + m16) * 72 + ks * 32 + q * 8]);
            #pragma unroll
            for (int mt = 0; mt < 4; ++mt)
                #pragma unroll
                for (int nt = 0; nt < 4; ++nt)
                    acc[mt][nt] = __builtin_amdgcn_mfma_f32_16x16x32_bf16(
                        af[mt], bfr[nt], acc[mt][nt], 0, 0, 0);
        }
    }
    float bcol[4];
    #pragma unroll
    for (int nt = 0; nt < 4; ++nt) bcol[nt] = bias[n0 + wn * 64 + nt * 16 + m16];
    #pragma unroll
    for (int mt = 0; mt < 4; ++mt)
        #pragma unroll
        for (int nt = 0; nt < 4; ++nt) {
            int gn = n0 + wn * 64 + nt * 16 + m16;
            #pragma unroll
            for (int r = 0; r < 4; ++r) {
                int gm = m0 + wm * 64 + mt * 16 + q * 4 + r;
                C[(size_t)gm * NCC + gn] = f2b(acc[mt][nt][r] + bcol[nt]);
            }
        }
}

// ---------------- scalar log2-domain LSTM gate (verified R8) ----------------
// Inputs prescaled: pi,pf,po = log2e*preact ; pg = 2*log2e*preact.
__device__ inline uchar_t lstm_gate(floatx4 a, ull_t xr, float& cc) {
    uint_t lo = (uint_t)xr, hi = (uint_t)(xr >> 32);
    float pi = a[0] + asf(lo << 16);
    float pf = a[1] + asf(lo & 0xffff0000u);
    float pg = a[2] + asf(hi << 16);
    float po = a[3] + asf(hi & 0xffff0000u);
    float ei = __builtin_amdgcn_exp2f(-fmaxf(pi, -40.f));   // e^-i
    float ef = __builtin_amdgcn_exp2f(-fmaxf(pf, -40.f));   // e^-f
    float eo = __builtin_amdgcn_exp2f(-fmaxf(po, -40.f));   // e^-o
    float ug = __builtin_amdgcn_exp2f(fminf(pg, 40.f));     // e^{2g}
    float A  = 1.f + ei, Bv = 1.f + ug, C = 1.f + ef;
    float AB  = A * Bv;
    float num = fmaf(Bv - 2.f, C, cc * AB);
    float cn  = num * __builtin_amdgcn_rcpf(C * AB);
    cc = cn;
    float uc = __builtin_amdgcn_exp2f(fminf(cn * 2.8853900817779268f, 40.f));
    float h  = (uc - 1.f) * __builtin_amdgcn_rcpf((uc + 1.f) * (1.f + eo));
    uint_t pk = __builtin_amdgcn_cvt_pk_fp8_f32(h, h, 0, false);
    return (uchar_t)(pk & 0xFF);
}

// ---------------- K3: recurrence, 64 WGs = 2 dirs x 32 batch-groups ---------
// 2 batches/WG.  512 threads = 8 waves; wave w computes gate rows
// [w*128, w*128+128) via 16 MFMA (16 cols, 2 valid).  Valid lanes (m16<2)
// store acc quads to accT (contiguous 128B per m-tile, conflict-free);
// after barrier each thread handles (hu = w*32+lane/2, batch = lane&1):
// one scalar gate, one ds_write_b8, one 8B xg load.
__global__ __launch_bounds__(512, 2) void lstm_k(const ushort_t* __restrict__ xg,
                                                 const uchar_t* __restrict__ whh8,
                                                 uchar_t* __restrict__ hhist8) {
    const int d  = blockIdx.x >> 5;             // direction
    const int bg = blockIdx.x & 31;             // batch group (2 batches)
    const int tid = threadIdx.x;
    const int w = tid >> 6, lane = tid & 63;
    const int q = lane >> 4, m16 = lane & 15;
    const int hu   = w * 32 + (lane >> 1);      // epilogue hidden unit
    const int bloc = lane & 1;                  // local batch 0..1
    const int blg  = bg * 2 + bloc;             // global batch

    __shared__ uchar_t hb8[2][16 * HPAD];       // fp8 h, [local batch][hu]
    __shared__ float   accT[2048];              // 8KB gate-quads [hu][b]
    for (int i = tid; i < 2 * 16 * HPAD; i += 512) ((uchar_t*)hb8)[i] = 0;

    // Weight A-frags: rows' w*128+mt*16+m16, k = kh*128 + q*32 (32B each).
    const uchar_t* wp = whh8 + (size_t)(d * NG + w * 128) * NH;
    v8i wreg[8][2];
    #pragma unroll
    for (int mt = 0; mt < 8; ++mt)
        #pragma unroll
        for (int kh = 0; kh < 2; ++kh)
            wreg[mt][kh] = *(const v8i*)(wp + (size_t)(mt * 16 + m16) * NH + kh * 128 + q * 32);
    #pragma unroll
    for (int mt = 0; mt < 8; ++mt)
        #pragma unroll
        for (int kh = 0; kh < 2; ++kh)
            asm volatile("" : "+a"(wreg[mt][kh]));   // pin in AGPR class

    float cc = 0.f;
    __syncthreads();

    const int scl = 0x7f7f7f7f;                 // e8m0 scale = 1.0 in all bytes
    // xg: this thread's 4 gate rows (hu) start at row hu*4 -> 8B.
    const ushort_t* xb_ = xg + (size_t)d * NG + hu * 4;

    ull_t xw, xwn;
    {
        const int t0 = d ? (NT - 1) : 0;
        xw = *(const ull_t*)(xb_ + (size_t)(t0 * NB + blg) * NCC);
    }

    #pragma unroll 1
    for (int s = 0; s < NT; ++s) {
        const int t = d ? (NT - 1 - s) : s;

        // Prefetch next step's xg (lands under MFMA + epilogue).
        if (s + 1 < NT) {
            const int tn = d ? (NT - 2 - s) : (s + 1);
            xwn = *(const ull_t*)(xb_ + (size_t)(tn * NB + blg) * NCC);
        }

        // B-frags: h_prev fp8 from LDS (rows 2-15 stay zero -> dead cols).
        const uchar_t* hrow = &hb8[s & 1][m16 * HPAD];
        v8i hf0 = *(const v8i*)(hrow + q * 32);
        v8i hf1 = *(const v8i*)(hrow + 128 + q * 32);

        floatx4 acc[8];
        #pragma unroll
        for (int mt = 0; mt < 8; ++mt) acc[mt] = (floatx4){0.f, 0.f, 0.f, 0.f};
        #pragma unroll
        for (int mt = 0; mt < 8; ++mt)
            acc[mt] = __builtin_amdgcn_mfma_scale_f32_16x16x128_f8f6f4(
                wreg[mt][0], hf0, acc[mt], 0, 0, 0, scl, 0, scl);
        #pragma unroll
        for (int mt = 0; mt < 8; ++mt)
            acc[mt] = __builtin_amdgcn_mfma_scale_f32_16x16x128_f8f6f4(
                wreg[mt][1], hf1, acc[mt], 0, 0, 0, scl, 0, scl);

        // acc transpose: valid lanes store their gate-quads.  For fixed mt
        // the 8 active lanes (q x m16<2) cover one contiguous 128B line.
        if (m16 < 2) {
            #pragma unroll
            for (int mt = 0; mt < 8; ++mt) {
                int hu_w = w * 32 + mt * 4 + q;
                *(floatx4*)((uchar_t*)accT + (size_t)hu_w * 32 + m16 * 16) = acc[mt];
            }
        }
        __syncthreads();                        // accT complete

        // Each thread: scalar gate for (hu, bloc); read is lane*16 contiguous.
        floatx4 a = *(const floatx4*)((const uchar_t*)accT + (size_t)hu * 32 + bloc * 16);
        uchar_t hv = lstm_gate(a, xw, cc);
        hb8[(s + 1) & 1][bloc * HPAD + hu] = hv;

        xw = xwn;
        __syncthreads();                        // h(s+1) complete

        // fp8 h-history: 2 batches x 256B = 512B/step/WG, 8B/thread.
        if (tid < 64) {
            int b_ = tid >> 5, off = (tid & 31) * 8;
            ull_t v = *(const ull_t*)(&hb8[(s + 1) & 1][b_ * HPAD + off]);
            *(ull_t*)(hhist8 + ((size_t)(d * NT + t) * NB + bg * 2 + b_) * NH + off) = v;
        }
    }
}

// ---------------- K4: em[t,b,l] = feats . W_lin[l] + b_lin ------------------
__global__ void em_k(const uchar_t* __restrict__ hhist8, const float* __restrict__ Wlin,
                     const float* __restrict__ blin, float* __restrict__ em) {
    const int t = blockIdx.x;
    const int tid = threadIdx.x;          // 576 threads
    __shared__ float Ws[NL * 520];
    for (int idx = tid; idx < NL * 2 * NH; idx += 576) {
        int l = idx >> 9, k = idx & 511;
        Ws[l * 520 + k] = Wlin[l * 2 * NH + k];
    }
    __syncthreads();
    const int b = tid / NL, l = tid - b * NL;
    const uchar_t* hf = hhist8 + ((size_t)t * NB + b) * NH;
    const uchar_t* hb = hhist8 + ((size_t)(NT + t) * NB + b) * NH;
    float acc = blin[l];
    #pragma unroll 4
    for (int kc = 0; kc < NH / 4; ++kc) {
        uint_t u = *(const uint_t*)(hf + kc * 4);
        floatx2 p0 = __builtin_amdgcn_cvt_pk_f32_fp8(u, false);
        floatx2 p1 = __builtin_amdgcn_cvt_pk_f32_fp8(u, true);
        acc += p0.x * Ws[l * 520 + kc * 4]     + p0.y * Ws[l * 520 + kc * 4 + 1]
             + p1.x * Ws[l * 520 + kc * 4 + 2] + p1.y * Ws[l * 520 + kc * 4 + 3];
    }
    #pragma unroll 4
    for (int kc = 0; kc < NH / 4; ++kc) {
        uint_t u = *(const uint_t*)(hb + kc * 4);
        floatx2 p0 = __builtin_amdgcn_cvt_pk_f32_fp8(u, false);
        floatx2 p1 = __builtin_amdgcn_cvt_pk_f32_fp8(u, true);
        acc += p0.x * Ws[l * 520 + NH + kc * 4]     + p0.y * Ws[l * 520 + NH + kc * 4 + 1]
             + p1.x * Ws[l * 520 + NH + kc * 4 + 2] + p1.y * Ws[l * 520 + NH + kc * 4 + 3];
    }
    em[((size_t)t * NB + b) * NL + l] = acc;
}

// ---------------- K5: CRF numerator per batch (parallel over t) -------------
__global__ void num_k(const float* __restrict__ em, const int* __restrict__ mask,
                      const int* __restrict__ labels, const float* __restrict__ start,
                      const float* __restrict__ endt, const float* __restrict__ trans,
                      float* __restrict__ numbuf) {
    const int b = blockIdx.x;       // 64 blocks x 64 threads (1 wave)
    const int lane = threadIdx.x;
    int cntm = 0;
    for (int t = lane; t < NT; t += 64) cntm += (mask[b * NT + t] != 0);
    #pragma unroll
    for (int off = 32; off > 0; off >>= 1) cntm += __shfl_down(cntm, off);
    const int len = __shfl(cntm, 0);

    float part = 0.f;
    for (int t = lane; t < NT; t += 64) {
        if (t >= 1 && t < len) {
            int tp = labels[b * NT + t - 1];
            int tg = labels[b * NT + t];
            part += trans[tp * NL + tg] + em[((size_t)t * NB + b) * NL + tg];
        }
    }
    #pragma unroll
    for (int off = 32; off > 0; off >>= 1) part += __shfl_down(part, off);
    if (lane == 0) {
        int tag0 = labels[b * NT];
        numbuf[b] = part + start[tag0] + em[(size_t)b * NL + tag0]
                  + endt[labels[b * NT + len - 1]];
    }
}

// ---------------- K6: CRF forward (logZ), diff = logZ - num -----------------
__global__ void crf_k(const float* __restrict__ em, const int* __restrict__ mask,
                      const float* __restrict__ start, const float* __restrict__ endt,
                      const float* __restrict__ trans, const float* __restrict__ numbuf,
                      float* __restrict__ diff) {
    const int b = blockIdx.x;
    const int lane = threadIdx.x;       // 64 threads = 1 wave
    int cnt = 0;
    for (int t = lane; t < NT; t += 64) cnt += (mask[b * NT + t] != 0);
    #pragma unroll
    for (int off = 32; off > 0; off >>= 1) cnt += __shfl_down(cnt, off);
    const int len = __shfl(cnt, 0);

    float tcol[NL];
    #pragma unroll
    for (int i = 0; i < NL; ++i) tcol[i] = (lane < NL) ? trans[i * NL + lane] : 0.f;
    float endv = (lane < NL) ? endt[lane] : 0.f;
    float score = (lane < NL) ? start[lane] + em[(size_t)b * NL + lane] : -1e30f;

    for (int t = 1; t < len; ++t) {
        float emv = (lane < NL) ? em[((size_t)t * NB + b) * NL + lane] : 0.f;
        float sv[NL];
        #pragma unroll
        for (int i = 0; i < NL; ++i) sv[i] = __shfl(score, i) + tcol[i];
        float m = sv[0];
        #pragma unroll
        for (int i = 1; i < NL; ++i) m = fmaxf(m, sv[i]);
        float sum = 0.f;
        #pragma unroll
        for (int i = 0; i < NL; ++i) sum += __expf(sv[i] - m);
        float nxt = m + __logf(sum) + emv;
        if (lane < NL) score = nxt;
    }
    float v = (lane < NL) ? score + endv : -1e30f;
    float m = -1e30f;
    float sv[NL];
    #pragma unroll
    for (int i = 0; i < NL; ++i) { sv[i] = __shfl(v, i); m = fmaxf(m, sv[i]); }
    float sum = 0.f;
    #pragma unroll
    for (int i = 0; i < NL; ++i) sum += __expf(sv[i] - m);
    float logZ = m + __logf(sum);
    if (lane == 0) diff[b] = logZ - numbuf[b];
}

// ---------------- K7: mean over batch -> d_out ------------------------------
__global__ void final_k(const float* __restrict__ diff, float* __restrict__ out) {
    float v = diff[threadIdx.x];
    #pragma unroll
    for (int off = 32; off > 0; off >>= 1) v += __shfl_down(v, off);
    if (threadIdx.x == 0) out[0] = v * (1.0f / NB);
}

extern "C" void kernel_launch(void* const* d_in, const int* in_sizes, int n_in,
                              void* d_out, int out_size, void* d_ws, size_t ws_size,
                              hipStream_t stream) {
    const float* emb   = (const float*)d_in[0];
    const float* Wihf  = (const float*)d_in[1];
    const float* Whhf  = (const float*)d_in[2];
    const float* bf    = (const float*)d_in[3];
    const float* Wihb  = (const float*)d_in[4];
    const float* Whhb  = (const float*)d_in[5];
    const float* bb    = (const float*)d_in[6];
    const float* Wlin  = (const float*)d_in[7];
    const float* blin  = (const float*)d_in[8];
    const float* start = (const float*)d_in[9];
    const float* endt  = (const float*)d_in[10];
    const float* trans = (const float*)d_in[11];
    const int*   mask  = (const int*)d_in[12];
    const int*   labels= (const int*)d_in[13];

    char* ws = (char*)d_ws;
    ushort_t* xbf   = (ushort_t*)(ws + 0);                     // 50,331,648
    ushort_t* wcat  = (ushort_t*)(ws + 50331648);              //  3,145,728
    uchar_t*  whh8  = (uchar_t*) (ws + 53477376);              //    524,288
    float*    bias  = (float*)   (ws + 54001664);              //      8,192
    ushort_t* xg    = (ushort_t*)(ws + 54009856);              // 134,217,728
    uchar_t*  hh8   = (uchar_t*) (ws + 188227584);             // 16,777,216
    float*    em    = (float*)   (ws + 205004800);             //  1,179,648
    float*    numb  = (float*)   (ws + 206184448);             //        256
    float*    diff  = (float*)   (ws + 206184704);             //        256

    conv_x<<<NT * NB * (NE / 4) / 256, 256, 0, stream>>>(emb, xbf);
    conv_w<<<(NCC * NE + NCC * NH / 2 + NCC) / 256, 256, 0, stream>>>(
        Wihf, Wihb, Whhf, Whhb, bf, bb, wcat, whh8, bias);
    gemm_xg<<<dim3(NCC / 128, NT * NB / 128), 256, 0, stream>>>(xbf, wcat, bias, xg);
    lstm_k<<<64, 512, 0, stream>>>(xg, whh8, hh8);
    em_k<<<NT, 576, 0, stream>>>(hh8, Wlin, blin, em);
    num_k<<<NB, 64, 0, stream>>>(em, mask, labels, start, endt, trans, numb);
    crf_k<<<NB, 64, 0, stream>>>(em, mask, start, endt, trans, numb, diff);
    final_k<<<1, 64, 0, stream>>>(diff, (float*)d_out);
}